// Round 10
// baseline (94.723 us; speedup 1.0000x reference)
//
#include <hip/hip_runtime.h>
#include <math.h>

#define HID 64

typedef __attribute__((ext_vector_type(4))) float f32x4;
typedef __attribute__((ext_vector_type(8))) __bf16 bf16x8;
typedef __attribute__((ext_vector_type(4))) __bf16 bf16x4;

__device__ __forceinline__ float fast_tanh(float x) {
    // tanh(x) = 1 - 2/(exp(2x)+1); exp overflow -> inf -> rcp -> 0 -> 1 (correct)
    float e = __expf(2.0f * x);
    return 1.0f - 2.0f * __builtin_amdgcn_rcpf(e + 1.0f);
}

// ---- prep: bf16 weight tables (W2, W2^T) + E_des, all into d_ws ----
__global__ void prep_kernel(const float* __restrict__ W1, const float* __restrict__ b1,
                            const float* __restrict__ W2, const float* __restrict__ b2,
                            const float* __restrict__ W3, const float* __restrict__ b3,
                            const float* __restrict__ x0, float* __restrict__ edes_out,
                            __bf16* __restrict__ W2bf, __bf16* __restrict__ W2Tbf) {
    int tid = threadIdx.x;  // 256 threads
    for (int idx = tid; idx < HID * HID; idx += 256) {
        W2bf[idx] = (__bf16)W2[idx];
        int r = idx >> 6, c = idx & 63;
        W2Tbf[idx] = (__bf16)W2[c * HID + r];
    }
    if (tid < 64) {
        int j = tid;
        float q1 = x0[0], q2 = x0[1], p1 = x0[2], p2 = x0[3];
        float h1j = fast_tanh(fmaf(q1, W1[j], fmaf(q2, W1[HID + j], b1[j])));
        float z = b2[j];
#pragma unroll 1
        for (int i = 0; i < HID; i++) {
            float hi = __shfl(h1j, i, 64);
            z = fmaf(hi, W2[i * HID + j], z);
        }
        float h2 = fast_tanh(z);
        float v = h2 * W3[j];
#pragma unroll
        for (int off = 32; off; off >>= 1) v += __shfl_xor(v, off, 64);
        if (j == 0) {
            float V = v + b3[0];
            float s, c;
            __sincosf(q2, &s, &c);
            float DEN = 2.0f - c * c;
            float rDEN = __builtin_amdgcn_rcpf(DEN);
            float quad = (p1 * p1 - 2.0f * (c + 1.0f) * p1 * p2 + (2.0f * c + 3.0f) * p2 * p2) * rDEN;
            float kin = 0.5f * quad;
            float s1, c1;
            __sincosf(q1, &s1, &c1);
            float c12 = c1 * c - s1 * s;
            float dq = 1.57079632679489662f - q2;
            float pot = -9.81f * (c12 + 2.0f * c1) + 0.5f * dq * dq;
            edes_out[0] = pot + kin + V;
        }
    }
}

// layer-1 half-fragment: 8 tanh from named float4s, no local arrays
#define L1HALF(AFRAG, K0)                                                          \
    do {                                                                           \
        const float4 wa0 = *(const float4*)(W1 + (K0));                            \
        const float4 wa1 = *(const float4*)(W1 + (K0) + 4);                        \
        const float4 wb0 = *(const float4*)(W1 + HID + (K0));                      \
        const float4 wb1 = *(const float4*)(W1 + HID + (K0) + 4);                  \
        const float4 bb0 = *(const float4*)(b1 + (K0));                            \
        const float4 bb1 = *(const float4*)(b1 + (K0) + 4);                        \
        AFRAG[0] = (__bf16)fast_tanh(fmaf(q1, wa0.x, fmaf(q2, wb0.x, bb0.x)));     \
        AFRAG[1] = (__bf16)fast_tanh(fmaf(q1, wa0.y, fmaf(q2, wb0.y, bb0.y)));     \
        AFRAG[2] = (__bf16)fast_tanh(fmaf(q1, wa0.z, fmaf(q2, wb0.z, bb0.z)));     \
        AFRAG[3] = (__bf16)fast_tanh(fmaf(q1, wa0.w, fmaf(q2, wb0.w, bb0.w)));     \
        AFRAG[4] = (__bf16)fast_tanh(fmaf(q1, wa1.x, fmaf(q2, wb1.x, bb1.x)));     \
        AFRAG[5] = (__bf16)fast_tanh(fmaf(q1, wa1.y, fmaf(q2, wb1.y, bb1.y)));     \
        AFRAG[6] = (__bf16)fast_tanh(fmaf(q1, wa1.z, fmaf(q2, wb1.z, bb1.z)));     \
        AFRAG[7] = (__bf16)fast_tanh(fmaf(q1, wa1.w, fmaf(q2, wb1.w, bb1.w)));     \
    } while (0)

// tanh + V partial + g2 pack/store for one m-tile (Z is a named f32x4; j = 16*MT+4*hi+r)
#define H2MT(Z, MT)                                                                \
    do {                                                                           \
        const float4 w3v = *(const float4*)(W3 + 16 * (MT) + 4 * hi);              \
        float h, g0_, g1_, g2_, g3_;                                               \
        h = fast_tanh(Z[0]); vp = fmaf(h, w3v.x, vp); g0_ = w3v.x * (1.0f - h * h);\
        h = fast_tanh(Z[1]); vp = fmaf(h, w3v.y, vp); g1_ = w3v.y * (1.0f - h * h);\
        h = fast_tanh(Z[2]); vp = fmaf(h, w3v.z, vp); g2_ = w3v.z * (1.0f - h * h);\
        h = fast_tanh(Z[3]); vp = fmaf(h, w3v.w, vp); g3_ = w3v.w * (1.0f - h * h);\
        bf16x4 gv = {(__bf16)g0_, (__bf16)g1_, (__bf16)g2_, (__bf16)g3_};          \
        *(bf16x4*)(g2buf + rowbase + ((16 * (MT) + 4 * hi) ^ swz)) = gv;           \
    } while (0)

// backward partials for one m-tile (RB is a named f32x4; i = 16*MT+4*hi+r)
#define DVMT(RB, MT)                                                                          \
    do {                                                                                      \
        const bf16x4 hv = *(const bf16x4*)(h1buf + rowbase + ((16 * (MT) + 4 * hi) ^ swz));   \
        const float4 w1av = *(const float4*)(W1 + 16 * (MT) + 4 * hi);                        \
        const float4 w1bv = *(const float4*)(W1 + HID + 16 * (MT) + 4 * hi);                  \
        float hf, gi;                                                                         \
        hf = (float)hv[0]; gi = (1.0f - hf * hf) * RB[0]; d1 = fmaf(w1av.x, gi, d1); d2 = fmaf(w1bv.x, gi, d2); \
        hf = (float)hv[1]; gi = (1.0f - hf * hf) * RB[1]; d1 = fmaf(w1av.y, gi, d1); d2 = fmaf(w1bv.y, gi, d2); \
        hf = (float)hv[2]; gi = (1.0f - hf * hf) * RB[2]; d1 = fmaf(w1av.z, gi, d1); d2 = fmaf(w1bv.z, gi, d2); \
        hf = (float)hv[3]; gi = (1.0f - hf * hf) * RB[3]; d1 = fmaf(w1av.w, gi, d1); d2 = fmaf(w1bv.w, gi, d2); \
    } while (0)

// ---- main: 16 batch rows per wave; swapped-operand MFMA (C cols = batch rows) ----
__global__ __launch_bounds__(256, 4) void pend_kernel(
    const float4* __restrict__ x,
    const float* __restrict__ W1, const float* __restrict__ b1,
    const __bf16* __restrict__ W2bf, const __bf16* __restrict__ W2Tbf,
    const float* __restrict__ b2,
    const float* __restrict__ W3, const float* __restrict__ b3,
    const float* __restrict__ Tp, const float* __restrict__ edes_p,
    float4* __restrict__ out, int n)
{
    __shared__ __align__(16) __bf16 lds[4 * 2048];  // per wave: h1[16][64], g2[16][64]
    const int tid = threadIdx.x;
    const int w = tid >> 6, l = tid & 63;
    const int lo = l & 15, hi = l >> 4;
    __bf16* h1buf = lds + w * 2048;
    __bf16* g2buf = h1buf + 1024;

    const float E_des = edes_p[0];
    const float Tabs = fabsf(Tp[0]);

    const int base = blockIdx.x * 64 + w * 16;
    int e = base + lo;
    if (e >= n) e = n - 1;
    const float4 xv = x[e];                 // lane holds x of batch row m = lo
    const float q1 = xv.x, q2 = xv.y, p1 = xv.z, p2 = xv.w;

    const int swz = (lo & 7) << 3;          // XOR swizzle on j (bits 3..5)
    const int rowbase = lo * HID;

    // ---- layer-1: lane holds h1[batch=lo][i = 8*hi + t (+32)] -> B-fragment of H1^T ----
    bf16x8 a10, a11;
    L1HALF(a10, 8 * hi);
    L1HALF(a11, 32 + 8 * hi);
    *(bf16x8*)(h1buf + rowbase + ((8 * hi) ^ swz))      = a10;
    *(bf16x8*)(h1buf + rowbase + ((32 + 8 * hi) ^ swz)) = a11;

    // fragment pointers (A-operands, weight tables; + mt*1024 + kh*32)
    const __bf16* w2t = W2Tbf + lo * HID + 8 * hi;
    const __bf16* w2b = W2bf  + lo * HID + 8 * hi;

    // ---- GEMM1 (swapped): Z2^T = W2^T @ H1^T ; C: col=batch(lo), row j=16*mt+4*hi+r ----
    const float4 b2v0 = *(const float4*)(b2 + 4 * hi);
    const float4 b2v1 = *(const float4*)(b2 + 16 + 4 * hi);
    const float4 b2v2 = *(const float4*)(b2 + 32 + 4 * hi);
    const float4 b2v3 = *(const float4*)(b2 + 48 + 4 * hi);
    f32x4 z0 = {b2v0.x, b2v0.y, b2v0.z, b2v0.w};
    f32x4 z1 = {b2v1.x, b2v1.y, b2v1.z, b2v1.w};
    f32x4 z2 = {b2v2.x, b2v2.y, b2v2.z, b2v2.w};
    f32x4 z3 = {b2v3.x, b2v3.y, b2v3.z, b2v3.w};
    z0 = __builtin_amdgcn_mfma_f32_16x16x32_bf16(*(const bf16x8*)(w2t + 0),    a10, z0, 0, 0, 0);
    z0 = __builtin_amdgcn_mfma_f32_16x16x32_bf16(*(const bf16x8*)(w2t + 32),   a11, z0, 0, 0, 0);
    z1 = __builtin_amdgcn_mfma_f32_16x16x32_bf16(*(const bf16x8*)(w2t + 1024), a10, z1, 0, 0, 0);
    z1 = __builtin_amdgcn_mfma_f32_16x16x32_bf16(*(const bf16x8*)(w2t + 1056), a11, z1, 0, 0, 0);
    z2 = __builtin_amdgcn_mfma_f32_16x16x32_bf16(*(const bf16x8*)(w2t + 2048), a10, z2, 0, 0, 0);
    z2 = __builtin_amdgcn_mfma_f32_16x16x32_bf16(*(const bf16x8*)(w2t + 2080), a11, z2, 0, 0, 0);
    z3 = __builtin_amdgcn_mfma_f32_16x16x32_bf16(*(const bf16x8*)(w2t + 3072), a10, z3, 0, 0, 0);
    z3 = __builtin_amdgcn_mfma_f32_16x16x32_bf16(*(const bf16x8*)(w2t + 3104), a11, z3, 0, 0, 0);

    // ---- h2/V/g2: all values belong to THIS lane's batch row ----
    float vp = 0.0f;
    H2MT(z0, 0);
    H2MT(z1, 1);
    H2MT(z2, 2);
    H2MT(z3, 3);

    // ---- GEMM2 (swapped): R^T = W2 @ G2^T ; B = g2 of own row, k-slice j=8*hi(+32) ----
    const bf16x8 a20 = *(const bf16x8*)(g2buf + rowbase + ((8 * hi) ^ swz));
    const bf16x8 a21 = *(const bf16x8*)(g2buf + rowbase + ((32 + 8 * hi) ^ swz));
    f32x4 r0 = {0.f, 0.f, 0.f, 0.f};
    f32x4 r1 = {0.f, 0.f, 0.f, 0.f};
    f32x4 r2 = {0.f, 0.f, 0.f, 0.f};
    f32x4 r3 = {0.f, 0.f, 0.f, 0.f};
    r0 = __builtin_amdgcn_mfma_f32_16x16x32_bf16(*(const bf16x8*)(w2b + 0),    a20, r0, 0, 0, 0);
    r0 = __builtin_amdgcn_mfma_f32_16x16x32_bf16(*(const bf16x8*)(w2b + 32),   a21, r0, 0, 0, 0);
    r1 = __builtin_amdgcn_mfma_f32_16x16x32_bf16(*(const bf16x8*)(w2b + 1024), a20, r1, 0, 0, 0);
    r1 = __builtin_amdgcn_mfma_f32_16x16x32_bf16(*(const bf16x8*)(w2b + 1056), a21, r1, 0, 0, 0);
    r2 = __builtin_amdgcn_mfma_f32_16x16x32_bf16(*(const bf16x8*)(w2b + 2048), a20, r2, 0, 0, 0);
    r2 = __builtin_amdgcn_mfma_f32_16x16x32_bf16(*(const bf16x8*)(w2b + 2080), a21, r2, 0, 0, 0);
    r3 = __builtin_amdgcn_mfma_f32_16x16x32_bf16(*(const bf16x8*)(w2b + 3072), a20, r3, 0, 0, 0);
    r3 = __builtin_amdgcn_mfma_f32_16x16x32_bf16(*(const bf16x8*)(w2b + 3104), a21, r3, 0, 0, 0);

    // ---- backward partials (own row), then 2-step cross-hi reduce ----
    float d1 = 0.0f, d2 = 0.0f;
    DVMT(r0, 0);
    DVMT(r1, 1);
    DVMT(r2, 2);
    DVMT(r3, 3);

    vp += __shfl_xor(vp, 16, 64);  vp += __shfl_xor(vp, 32, 64);
    d1 += __shfl_xor(d1, 16, 64);  d1 += __shfl_xor(d1, 32, 64);
    d2 += __shfl_xor(d2, 16, 64);  d2 += __shfl_xor(d2, 32, 64);

    const float V = vp + b3[0];
    const float dVq1 = d1, dVq2 = d2;

    // ---- physics (L1=L2=M1=M2=1, G=9.81, K1=0.5, A_E=1, B_DAMP=0) ----
    float s2q, c2q, s1q, c1q;
    __sincosf(q2, &s2q, &c2q);
    __sincosf(q1, &s1q, &c1q);
    float s12 = s1q * c2q + c1q * s2q;
    float c12 = c1q * c2q - s1q * s2q;

    float cc = c2q, s = s2q;
    float DEN = 2.0f - cc * cc;          // == 1 + s^2
    float rDEN = __builtin_amdgcn_rcpf(DEN);
    float cp1 = cc + 1.0f;

    float quad = (p1 * p1 - 2.0f * cp1 * p1 * p2 + (2.0f * cc + 3.0f) * p2 * p2) * rDEN;
    float kin = 0.5f * quad;
    float dqa = 1.57079632679489662f - q2;
    float pot = -9.81f * (c12 + 2.0f * c1q) + 0.5f * dqa * dqa;
    float E = pot + kin + V;

    float fac = (quad > 0.0f) ? __builtin_amdgcn_rsqf(quad) : 1.0f;
    float coef = E_des - E;
    float u1 = -dVq1 + coef * p1 * fac;
    float u2 = -dVq2 + coef * p2 * fac;

    float dq1dt = (p1 - cp1 * p2) * rDEN;
    float dq2dt = ((2.0f * cc + 3.0f) * p2 - cp1 * p1) * rDEN;
    float dp1dt = -9.81f * (s12 + 2.0f * s1q) + u1;

    float inner = -p2 * p2 * s * cp1 * (cc + 2.0f)
                + p1 * p2 * s * (fmaf(cc, cc, fmaf(2.0f, cc, 2.0f)))
                - cc * p1 * p1 * s
                + DEN * DEN * (fmaf(9.81f, s12, -0.5f * (3.14159265358979324f - 2.0f * q2)));
    float dp2dt = -(inner * rDEN * rDEN) + u2;

    if (l < 16 && base + lo < n) {
        float4 o;
        o.x = Tabs * dq1dt;
        o.y = Tabs * dq2dt;
        o.z = Tabs * dp1dt;
        o.w = Tabs * dp2dt;
        out[base + lo] = o;
    }
}

extern "C" void kernel_launch(void* const* d_in, const int* in_sizes, int n_in,
                              void* d_out, int out_size, void* d_ws, size_t ws_size,
                              hipStream_t stream) {
    const float* x  = (const float*)d_in[0];
    // d_in[1] = t (unused)
    const float* W1 = (const float*)d_in[2];
    const float* b1 = (const float*)d_in[3];
    const float* W2 = (const float*)d_in[4];
    const float* b2 = (const float*)d_in[5];
    const float* W3 = (const float*)d_in[6];
    const float* b3 = (const float*)d_in[7];
    const float* Tp = (const float*)d_in[8];
    const float* x0 = (const float*)d_in[9];

    float* ws = (float*)d_ws;
    float* edes = ws;                                   // 1 float (+ padding to 64B)
    __bf16* W2bf  = (__bf16*)(ws + 16);                 // 4096 bf16 = 8 KB
    __bf16* W2Tbf = W2bf + HID * HID;                   // 4096 bf16 = 8 KB

    prep_kernel<<<1, 256, 0, stream>>>(W1, b1, W2, b2, W3, b3, x0, edes, W2bf, W2Tbf);

    int n = in_sizes[0] / 4;  // 500000
    int blocks = (n + 63) / 64;  // 64 elements per 256-thread block (16 per wave)
    pend_kernel<<<blocks, 256, 0, stream>>>((const float4*)x, W1, b1, W2bf, W2Tbf,
                                            b2, W3, b3, Tp, edes, (float4*)d_out, n);
}

// Round 11
// 67.690 us; speedup vs baseline: 1.3994x; 1.3994x over previous
//
#include <hip/hip_runtime.h>
#include <math.h>

#define HID 64

typedef __attribute__((ext_vector_type(4))) float f32x4;
typedef __attribute__((ext_vector_type(8))) __bf16 bf16x8;
typedef __attribute__((ext_vector_type(4))) __bf16 bf16x4;

__device__ __forceinline__ float fast_tanh(float x) {
    // tanh(x) = 1 - 2/(exp(2x)+1); exp overflow -> inf -> rcp -> 0 -> 1 (correct)
    float e = __expf(2.0f * x);
    return 1.0f - 2.0f * __builtin_amdgcn_rcpf(e + 1.0f);
}

// ---- prep: bf16 weight tables (W2, W2^T) + E_des, all into d_ws ----
__global__ void prep_kernel(const float* __restrict__ W1, const float* __restrict__ b1,
                            const float* __restrict__ W2, const float* __restrict__ b2,
                            const float* __restrict__ W3, const float* __restrict__ b3,
                            const float* __restrict__ x0, float* __restrict__ edes_out,
                            __bf16* __restrict__ W2bf, __bf16* __restrict__ W2Tbf) {
    int tid = threadIdx.x;  // 256 threads
    for (int idx = tid; idx < HID * HID; idx += 256) {
        W2bf[idx] = (__bf16)W2[idx];
        int r = idx >> 6, c = idx & 63;
        W2Tbf[idx] = (__bf16)W2[c * HID + r];
    }
    if (tid < 64) {
        int j = tid;
        float q1 = x0[0], q2 = x0[1], p1 = x0[2], p2 = x0[3];
        float h1j = fast_tanh(fmaf(q1, W1[j], fmaf(q2, W1[HID + j], b1[j])));
        float z = b2[j];
#pragma unroll 1
        for (int i = 0; i < HID; i++) {
            float hi = __shfl(h1j, i, 64);
            z = fmaf(hi, W2[i * HID + j], z);
        }
        float h2 = fast_tanh(z);
        float v = h2 * W3[j];
#pragma unroll
        for (int off = 32; off; off >>= 1) v += __shfl_xor(v, off, 64);
        if (j == 0) {
            float V = v + b3[0];
            float s, c;
            __sincosf(q2, &s, &c);
            float DEN = 2.0f - c * c;
            float rDEN = __builtin_amdgcn_rcpf(DEN);
            float quad = (p1 * p1 - 2.0f * (c + 1.0f) * p1 * p2 + (2.0f * c + 3.0f) * p2 * p2) * rDEN;
            float kin = 0.5f * quad;
            float s1, c1;
            __sincosf(q1, &s1, &c1);
            float c12 = c1 * c - s1 * s;
            float dq = 1.57079632679489662f - q2;
            float pot = -9.81f * (c12 + 2.0f * c1) + 0.5f * dq * dq;
            edes_out[0] = pot + kin + V;
        }
    }
}

// dual layer-1 half-fragment: one set of weight loads feeds BOTH tiles
#define L1HALF2(FA, FB, K0)                                                         \
    do {                                                                            \
        const float4 wa0 = *(const float4*)(W1 + (K0));                             \
        const float4 wa1 = *(const float4*)(W1 + (K0) + 4);                         \
        const float4 wb0 = *(const float4*)(W1 + HID + (K0));                       \
        const float4 wb1 = *(const float4*)(W1 + HID + (K0) + 4);                   \
        const float4 bb0 = *(const float4*)(b1 + (K0));                             \
        const float4 bb1 = *(const float4*)(b1 + (K0) + 4);                         \
        FA[0] = (__bf16)fast_tanh(fmaf(q1A, wa0.x, fmaf(q2A, wb0.x, bb0.x)));       \
        FA[1] = (__bf16)fast_tanh(fmaf(q1A, wa0.y, fmaf(q2A, wb0.y, bb0.y)));       \
        FA[2] = (__bf16)fast_tanh(fmaf(q1A, wa0.z, fmaf(q2A, wb0.z, bb0.z)));       \
        FA[3] = (__bf16)fast_tanh(fmaf(q1A, wa0.w, fmaf(q2A, wb0.w, bb0.w)));       \
        FA[4] = (__bf16)fast_tanh(fmaf(q1A, wa1.x, fmaf(q2A, wb1.x, bb1.x)));       \
        FA[5] = (__bf16)fast_tanh(fmaf(q1A, wa1.y, fmaf(q2A, wb1.y, bb1.y)));       \
        FA[6] = (__bf16)fast_tanh(fmaf(q1A, wa1.z, fmaf(q2A, wb1.z, bb1.z)));       \
        FA[7] = (__bf16)fast_tanh(fmaf(q1A, wa1.w, fmaf(q2A, wb1.w, bb1.w)));       \
        FB[0] = (__bf16)fast_tanh(fmaf(q1B, wa0.x, fmaf(q2B, wb0.x, bb0.x)));       \
        FB[1] = (__bf16)fast_tanh(fmaf(q1B, wa0.y, fmaf(q2B, wb0.y, bb0.y)));       \
        FB[2] = (__bf16)fast_tanh(fmaf(q1B, wa0.z, fmaf(q2B, wb0.z, bb0.z)));       \
        FB[3] = (__bf16)fast_tanh(fmaf(q1B, wa0.w, fmaf(q2B, wb0.w, bb0.w)));       \
        FB[4] = (__bf16)fast_tanh(fmaf(q1B, wa1.x, fmaf(q2B, wb1.x, bb1.x)));       \
        FB[5] = (__bf16)fast_tanh(fmaf(q1B, wa1.y, fmaf(q2B, wb1.y, bb1.y)));       \
        FB[6] = (__bf16)fast_tanh(fmaf(q1B, wa1.z, fmaf(q2B, wb1.z, bb1.z)));       \
        FB[7] = (__bf16)fast_tanh(fmaf(q1B, wa1.w, fmaf(q2B, wb1.w, bb1.w)));       \
    } while (0)

// tanh + V partial + g2 pack/store for one m-tile of one tile's Z
#define H2MT(Z, MT, VP, GBUF)                                                       \
    do {                                                                            \
        const float4 w3v = *(const float4*)(W3 + 16 * (MT) + 4 * hi);               \
        float h, g0_, g1_, g2_, g3_;                                                \
        h = fast_tanh(Z[0]); VP = fmaf(h, w3v.x, VP); g0_ = w3v.x * (1.0f - h * h); \
        h = fast_tanh(Z[1]); VP = fmaf(h, w3v.y, VP); g1_ = w3v.y * (1.0f - h * h); \
        h = fast_tanh(Z[2]); VP = fmaf(h, w3v.z, VP); g2_ = w3v.z * (1.0f - h * h); \
        h = fast_tanh(Z[3]); VP = fmaf(h, w3v.w, VP); g3_ = w3v.w * (1.0f - h * h); \
        bf16x4 gv = {(__bf16)g0_, (__bf16)g1_, (__bf16)g2_, (__bf16)g3_};           \
        *(bf16x4*)((GBUF) + rowbase + ((16 * (MT) + 4 * hi) ^ swz)) = gv;           \
    } while (0)

// backward partials for one m-tile, BOTH tiles; h1 recomputed (no LDS)
#define DVMT2(RA, RB, MT)                                                                       \
    do {                                                                                        \
        const float4 w1av = *(const float4*)(W1 + 16 * (MT) + 4 * hi);                          \
        const float4 w1bv = *(const float4*)(W1 + HID + 16 * (MT) + 4 * hi);                    \
        const float4 b1v  = *(const float4*)(b1 + 16 * (MT) + 4 * hi);                          \
        float hf, gi;                                                                           \
        hf = fast_tanh(fmaf(q1A, w1av.x, fmaf(q2A, w1bv.x, b1v.x)));                            \
        gi = (1.0f - hf * hf) * RA[0]; d1A = fmaf(w1av.x, gi, d1A); d2A = fmaf(w1bv.x, gi, d2A);\
        hf = fast_tanh(fmaf(q1A, w1av.y, fmaf(q2A, w1bv.y, b1v.y)));                            \
        gi = (1.0f - hf * hf) * RA[1]; d1A = fmaf(w1av.y, gi, d1A); d2A = fmaf(w1bv.y, gi, d2A);\
        hf = fast_tanh(fmaf(q1A, w1av.z, fmaf(q2A, w1bv.z, b1v.z)));                            \
        gi = (1.0f - hf * hf) * RA[2]; d1A = fmaf(w1av.z, gi, d1A); d2A = fmaf(w1bv.z, gi, d2A);\
        hf = fast_tanh(fmaf(q1A, w1av.w, fmaf(q2A, w1bv.w, b1v.w)));                            \
        gi = (1.0f - hf * hf) * RA[3]; d1A = fmaf(w1av.w, gi, d1A); d2A = fmaf(w1bv.w, gi, d2A);\
        hf = fast_tanh(fmaf(q1B, w1av.x, fmaf(q2B, w1bv.x, b1v.x)));                            \
        gi = (1.0f - hf * hf) * RB[0]; d1B = fmaf(w1av.x, gi, d1B); d2B = fmaf(w1bv.x, gi, d2B);\
        hf = fast_tanh(fmaf(q1B, w1av.y, fmaf(q2B, w1bv.y, b1v.y)));                            \
        gi = (1.0f - hf * hf) * RB[1]; d1B = fmaf(w1av.y, gi, d1B); d2B = fmaf(w1bv.y, gi, d2B);\
        hf = fast_tanh(fmaf(q1B, w1av.z, fmaf(q2B, w1bv.z, b1v.z)));                            \
        gi = (1.0f - hf * hf) * RB[2]; d1B = fmaf(w1av.z, gi, d1B); d2B = fmaf(w1bv.z, gi, d2B);\
        hf = fast_tanh(fmaf(q1B, w1av.w, fmaf(q2B, w1bv.w, b1v.w)));                            \
        gi = (1.0f - hf * hf) * RB[3]; d1B = fmaf(w1av.w, gi, d1B); d2B = fmaf(w1bv.w, gi, d2B);\
    } while (0)

// reduce + physics + store for one tile
#define FINISH(Q1, Q2, P1, P2, VP, D1, D2, ROW)                                     \
    do {                                                                            \
        VP += __shfl_xor(VP, 16, 64);  VP += __shfl_xor(VP, 32, 64);                \
        D1 += __shfl_xor(D1, 16, 64);  D1 += __shfl_xor(D1, 32, 64);                \
        D2 += __shfl_xor(D2, 16, 64);  D2 += __shfl_xor(D2, 32, 64);                \
        const float V = VP + b3c;                                                   \
        float s2q, c2q, s1q, c1q;                                                   \
        __sincosf(Q2, &s2q, &c2q);                                                  \
        __sincosf(Q1, &s1q, &c1q);                                                  \
        const float s12 = s1q * c2q + c1q * s2q;                                    \
        const float c12 = c1q * c2q - s1q * s2q;                                    \
        const float cc = c2q, s = s2q;                                              \
        const float DEN = 2.0f - cc * cc;                                           \
        const float rDEN = __builtin_amdgcn_rcpf(DEN);                              \
        const float cp1 = cc + 1.0f;                                                \
        const float quad = (P1 * P1 - 2.0f * cp1 * P1 * P2 + (2.0f * cc + 3.0f) * P2 * P2) * rDEN; \
        const float kin = 0.5f * quad;                                              \
        const float dqa = 1.57079632679489662f - Q2;                                \
        const float pot = -9.81f * (c12 + 2.0f * c1q) + 0.5f * dqa * dqa;           \
        const float E = pot + kin + V;                                              \
        const float fac = (quad > 0.0f) ? __builtin_amdgcn_rsqf(quad) : 1.0f;       \
        const float coef = E_des - E;                                               \
        const float u1 = -D1 + coef * P1 * fac;                                     \
        const float u2 = -D2 + coef * P2 * fac;                                     \
        const float dq1dt = (P1 - cp1 * P2) * rDEN;                                 \
        const float dq2dt = ((2.0f * cc + 3.0f) * P2 - cp1 * P1) * rDEN;            \
        const float dp1dt = -9.81f * (s12 + 2.0f * s1q) + u1;                       \
        const float inner = -P2 * P2 * s * cp1 * (cc + 2.0f)                        \
                    + P1 * P2 * s * (fmaf(cc, cc, fmaf(2.0f, cc, 2.0f)))            \
                    - cc * P1 * P1 * s                                              \
                    + DEN * DEN * (fmaf(9.81f, s12, -0.5f * (3.14159265358979324f - 2.0f * Q2))); \
        const float dp2dt = -(inner * rDEN * rDEN) + u2;                            \
        if (l < 16 && (ROW) < n) {                                                  \
            float4 o;                                                               \
            o.x = Tabs * dq1dt;                                                     \
            o.y = Tabs * dq2dt;                                                     \
            o.z = Tabs * dp1dt;                                                     \
            o.w = Tabs * dp2dt;                                                     \
            out[(ROW)] = o;                                                         \
        }                                                                           \
    } while (0)

// ---- main: TWO interleaved 16-row tiles per wave (independent dep chains) ----
__global__ __launch_bounds__(256, 3) void pend_kernel(
    const float4* __restrict__ x,
    const float* __restrict__ W1, const float* __restrict__ b1,
    const __bf16* __restrict__ W2bf, const __bf16* __restrict__ W2Tbf,
    const float* __restrict__ b2,
    const float* __restrict__ W3, const float* __restrict__ b3,
    const float* __restrict__ Tp, const float* __restrict__ edes_p,
    float4* __restrict__ out, int n)
{
    __shared__ __align__(16) __bf16 lds[8 * 1024];  // per wave: g2A[16][64], g2B[16][64]
    const int tid = threadIdx.x;
    const int w = tid >> 6, l = tid & 63;
    const int lo = l & 15, hi = l >> 4;
    __bf16* g2A = lds + w * 2048;
    __bf16* g2B = g2A + 1024;

    const float E_des = edes_p[0];
    const float Tabs = fabsf(Tp[0]);
    const float b3c = b3[0];

    const int base = blockIdx.x * 128 + w * 32;   // 32 rows per wave
    const int rowA = base + lo;
    const int rowB = base + 16 + lo;
    int eA = rowA; if (eA >= n) eA = n - 1;
    int eB = rowB; if (eB >= n) eB = n - 1;
    const float4 xvA = x[eA];
    const float4 xvB = x[eB];
    const float q1A = xvA.x, q2A = xvA.y, p1A = xvA.z, p2A = xvA.w;
    const float q1B = xvB.x, q2B = xvB.y, p1B = xvB.z, p2B = xvB.w;

    const int swz = (lo & 7) << 3;          // XOR swizzle on j (bits 3..5)
    const int rowbase = lo * HID;

    // ---- layer-1 for both tiles (shared weight loads) ----
    bf16x8 a10A, a11A, a10B, a11B;
    L1HALF2(a10A, a10B, 8 * hi);
    L1HALF2(a11A, a11B, 32 + 8 * hi);

    // fragment pointers (A-operands, weight tables; + mt*1024 + kh*32)
    const __bf16* w2t = W2Tbf + lo * HID + 8 * hi;
    const __bf16* w2b = W2bf  + lo * HID + 8 * hi;

    // ---- GEMM1 (swapped): Z^T = W2^T @ H1^T for both tiles ----
    const float4 b2v0 = *(const float4*)(b2 + 4 * hi);
    const float4 b2v1 = *(const float4*)(b2 + 16 + 4 * hi);
    const float4 b2v2 = *(const float4*)(b2 + 32 + 4 * hi);
    const float4 b2v3 = *(const float4*)(b2 + 48 + 4 * hi);
    f32x4 zA0 = {b2v0.x, b2v0.y, b2v0.z, b2v0.w};
    f32x4 zA1 = {b2v1.x, b2v1.y, b2v1.z, b2v1.w};
    f32x4 zA2 = {b2v2.x, b2v2.y, b2v2.z, b2v2.w};
    f32x4 zA3 = {b2v3.x, b2v3.y, b2v3.z, b2v3.w};
    f32x4 zB0 = zA0, zB1 = zA1, zB2 = zA2, zB3 = zA3;
    zA0 = __builtin_amdgcn_mfma_f32_16x16x32_bf16(*(const bf16x8*)(w2t + 0),    a10A, zA0, 0, 0, 0);
    zB0 = __builtin_amdgcn_mfma_f32_16x16x32_bf16(*(const bf16x8*)(w2t + 0),    a10B, zB0, 0, 0, 0);
    zA0 = __builtin_amdgcn_mfma_f32_16x16x32_bf16(*(const bf16x8*)(w2t + 32),   a11A, zA0, 0, 0, 0);
    zB0 = __builtin_amdgcn_mfma_f32_16x16x32_bf16(*(const bf16x8*)(w2t + 32),   a11B, zB0, 0, 0, 0);
    zA1 = __builtin_amdgcn_mfma_f32_16x16x32_bf16(*(const bf16x8*)(w2t + 1024), a10A, zA1, 0, 0, 0);
    zB1 = __builtin_amdgcn_mfma_f32_16x16x32_bf16(*(const bf16x8*)(w2t + 1024), a10B, zB1, 0, 0, 0);
    zA1 = __builtin_amdgcn_mfma_f32_16x16x32_bf16(*(const bf16x8*)(w2t + 1056), a11A, zA1, 0, 0, 0);
    zB1 = __builtin_amdgcn_mfma_f32_16x16x32_bf16(*(const bf16x8*)(w2t + 1056), a11B, zB1, 0, 0, 0);
    zA2 = __builtin_amdgcn_mfma_f32_16x16x32_bf16(*(const bf16x8*)(w2t + 2048), a10A, zA2, 0, 0, 0);
    zB2 = __builtin_amdgcn_mfma_f32_16x16x32_bf16(*(const bf16x8*)(w2t + 2048), a10B, zB2, 0, 0, 0);
    zA2 = __builtin_amdgcn_mfma_f32_16x16x32_bf16(*(const bf16x8*)(w2t + 2080), a11A, zA2, 0, 0, 0);
    zB2 = __builtin_amdgcn_mfma_f32_16x16x32_bf16(*(const bf16x8*)(w2t + 2080), a11B, zB2, 0, 0, 0);
    zA3 = __builtin_amdgcn_mfma_f32_16x16x32_bf16(*(const bf16x8*)(w2t + 3072), a10A, zA3, 0, 0, 0);
    zB3 = __builtin_amdgcn_mfma_f32_16x16x32_bf16(*(const bf16x8*)(w2t + 3072), a10B, zB3, 0, 0, 0);
    zA3 = __builtin_amdgcn_mfma_f32_16x16x32_bf16(*(const bf16x8*)(w2t + 3104), a11A, zA3, 0, 0, 0);
    zB3 = __builtin_amdgcn_mfma_f32_16x16x32_bf16(*(const bf16x8*)(w2t + 3104), a11B, zB3, 0, 0, 0);

    // ---- h2/V/g2 for both tiles (lane-local rows) ----
    float vpA = 0.0f, vpB = 0.0f;
    H2MT(zA0, 0, vpA, g2A);
    H2MT(zB0, 0, vpB, g2B);
    H2MT(zA1, 1, vpA, g2A);
    H2MT(zB1, 1, vpB, g2B);
    H2MT(zA2, 2, vpA, g2A);
    H2MT(zB2, 2, vpB, g2B);
    H2MT(zA3, 3, vpA, g2A);
    H2MT(zB3, 3, vpB, g2B);

    // ---- GEMM2 (swapped): R^T = W2 @ G2^T for both tiles ----
    const bf16x8 a20A = *(const bf16x8*)(g2A + rowbase + ((8 * hi) ^ swz));
    const bf16x8 a21A = *(const bf16x8*)(g2A + rowbase + ((32 + 8 * hi) ^ swz));
    const bf16x8 a20B = *(const bf16x8*)(g2B + rowbase + ((8 * hi) ^ swz));
    const bf16x8 a21B = *(const bf16x8*)(g2B + rowbase + ((32 + 8 * hi) ^ swz));
    f32x4 rA0 = {0.f, 0.f, 0.f, 0.f}, rA1 = rA0, rA2 = rA0, rA3 = rA0;
    f32x4 rB0 = rA0, rB1 = rA0, rB2 = rA0, rB3 = rA0;
    rA0 = __builtin_amdgcn_mfma_f32_16x16x32_bf16(*(const bf16x8*)(w2b + 0),    a20A, rA0, 0, 0, 0);
    rB0 = __builtin_amdgcn_mfma_f32_16x16x32_bf16(*(const bf16x8*)(w2b + 0),    a20B, rB0, 0, 0, 0);
    rA0 = __builtin_amdgcn_mfma_f32_16x16x32_bf16(*(const bf16x8*)(w2b + 32),   a21A, rA0, 0, 0, 0);
    rB0 = __builtin_amdgcn_mfma_f32_16x16x32_bf16(*(const bf16x8*)(w2b + 32),   a21B, rB0, 0, 0, 0);
    rA1 = __builtin_amdgcn_mfma_f32_16x16x32_bf16(*(const bf16x8*)(w2b + 1024), a20A, rA1, 0, 0, 0);
    rB1 = __builtin_amdgcn_mfma_f32_16x16x32_bf16(*(const bf16x8*)(w2b + 1024), a20B, rB1, 0, 0, 0);
    rA1 = __builtin_amdgcn_mfma_f32_16x16x32_bf16(*(const bf16x8*)(w2b + 1056), a21A, rA1, 0, 0, 0);
    rB1 = __builtin_amdgcn_mfma_f32_16x16x32_bf16(*(const bf16x8*)(w2b + 1056), a21B, rB1, 0, 0, 0);
    rA2 = __builtin_amdgcn_mfma_f32_16x16x32_bf16(*(const bf16x8*)(w2b + 2048), a20A, rA2, 0, 0, 0);
    rB2 = __builtin_amdgcn_mfma_f32_16x16x32_bf16(*(const bf16x8*)(w2b + 2048), a20B, rB2, 0, 0, 0);
    rA2 = __builtin_amdgcn_mfma_f32_16x16x32_bf16(*(const bf16x8*)(w2b + 2080), a21A, rA2, 0, 0, 0);
    rB2 = __builtin_amdgcn_mfma_f32_16x16x32_bf16(*(const bf16x8*)(w2b + 2080), a21B, rB2, 0, 0, 0);
    rA3 = __builtin_amdgcn_mfma_f32_16x16x32_bf16(*(const bf16x8*)(w2b + 3072), a20A, rA3, 0, 0, 0);
    rB3 = __builtin_amdgcn_mfma_f32_16x16x32_bf16(*(const bf16x8*)(w2b + 3072), a20B, rB3, 0, 0, 0);
    rA3 = __builtin_amdgcn_mfma_f32_16x16x32_bf16(*(const bf16x8*)(w2b + 3104), a21A, rA3, 0, 0, 0);
    rB3 = __builtin_amdgcn_mfma_f32_16x16x32_bf16(*(const bf16x8*)(w2b + 3104), a21B, rB3, 0, 0, 0);

    // ---- backward partials (h1 recomputed, shared weight loads) ----
    float d1A = 0.0f, d2A = 0.0f, d1B = 0.0f, d2B = 0.0f;
    DVMT2(rA0, rB0, 0);
    DVMT2(rA1, rB1, 1);
    DVMT2(rA2, rB2, 2);
    DVMT2(rA3, rB3, 3);

    // ---- reduce + physics + store, both tiles ----
    FINISH(q1A, q2A, p1A, p2A, vpA, d1A, d2A, rowA);
    FINISH(q1B, q2B, p1B, p2B, vpB, d1B, d2B, rowB);
}

extern "C" void kernel_launch(void* const* d_in, const int* in_sizes, int n_in,
                              void* d_out, int out_size, void* d_ws, size_t ws_size,
                              hipStream_t stream) {
    const float* x  = (const float*)d_in[0];
    // d_in[1] = t (unused)
    const float* W1 = (const float*)d_in[2];
    const float* b1 = (const float*)d_in[3];
    const float* W2 = (const float*)d_in[4];
    const float* b2 = (const float*)d_in[5];
    const float* W3 = (const float*)d_in[6];
    const float* b3 = (const float*)d_in[7];
    const float* Tp = (const float*)d_in[8];
    const float* x0 = (const float*)d_in[9];

    float* ws = (float*)d_ws;
    float* edes = ws;                                   // 1 float (+ padding to 64B)
    __bf16* W2bf  = (__bf16*)(ws + 16);                 // 4096 bf16 = 8 KB
    __bf16* W2Tbf = W2bf + HID * HID;                   // 4096 bf16 = 8 KB

    prep_kernel<<<1, 256, 0, stream>>>(W1, b1, W2, b2, W3, b3, x0, edes, W2bf, W2Tbf);

    int n = in_sizes[0] / 4;  // 500000
    int blocks = (n + 127) / 128;  // 128 rows per block (4 waves x 2 tiles x 16) -> 3907
    pend_kernel<<<blocks, 256, 0, stream>>>((const float4*)x, W1, b1, W2bf, W2Tbf,
                                            b2, W3, b3, Tp, edes, (float4*)d_out, n);
}

// Round 12
// 51.494 us; speedup vs baseline: 1.8395x; 1.3145x over previous
//
#include <hip/hip_runtime.h>
#include <math.h>

#define HID 64

typedef __attribute__((ext_vector_type(4))) float f32x4;
typedef __attribute__((ext_vector_type(8))) __bf16 bf16x8;
typedef __attribute__((ext_vector_type(4))) __bf16 bf16x4;

__device__ __forceinline__ float fast_tanh(float x) {
    // tanh(x) = 1 - 2/(exp(2x)+1); exp overflow -> inf -> rcp -> 0 -> 1 (correct)
    float e = __expf(2.0f * x);
    return 1.0f - 2.0f * __builtin_amdgcn_rcpf(e + 1.0f);
}

// ---- prep: bf16 weight tables (W2, W2^T) + E_des, all into d_ws ----
__global__ void prep_kernel(const float* __restrict__ W1, const float* __restrict__ b1,
                            const float* __restrict__ W2, const float* __restrict__ b2,
                            const float* __restrict__ W3, const float* __restrict__ b3,
                            const float* __restrict__ x0, float* __restrict__ edes_out,
                            __bf16* __restrict__ W2bf, __bf16* __restrict__ W2Tbf) {
    int tid = threadIdx.x;  // 256 threads
    for (int idx = tid; idx < HID * HID; idx += 256) {
        W2bf[idx] = (__bf16)W2[idx];
        int r = idx >> 6, c = idx & 63;
        W2Tbf[idx] = (__bf16)W2[c * HID + r];
    }
    if (tid < 64) {
        int j = tid;
        float q1 = x0[0], q2 = x0[1], p1 = x0[2], p2 = x0[3];
        float h1j = fast_tanh(fmaf(q1, W1[j], fmaf(q2, W1[HID + j], b1[j])));
        float z = b2[j];
#pragma unroll 1
        for (int i = 0; i < HID; i++) {
            float hi = __shfl(h1j, i, 64);
            z = fmaf(hi, W2[i * HID + j], z);
        }
        float h2 = fast_tanh(z);
        float v = h2 * W3[j];
#pragma unroll
        for (int off = 32; off; off >>= 1) v += __shfl_xor(v, off, 64);
        if (j == 0) {
            float V = v + b3[0];
            float s, c;
            __sincosf(q2, &s, &c);
            float DEN = 2.0f - c * c;
            float rDEN = __builtin_amdgcn_rcpf(DEN);
            float quad = (p1 * p1 - 2.0f * (c + 1.0f) * p1 * p2 + (2.0f * c + 3.0f) * p2 * p2) * rDEN;
            float kin = 0.5f * quad;
            float s1, c1;
            __sincosf(q1, &s1, &c1);
            float c12 = c1 * c - s1 * s;
            float dq = 1.57079632679489662f - q2;
            float pot = -9.81f * (c12 + 2.0f * c1) + 0.5f * dq * dq;
            edes_out[0] = pot + kin + V;
        }
    }
}

// 8 tanh into fragment F for one tile (wa0..bb1 in scope)
#define TANH8(F, Q1v, Q2v)                                                  \
    F[0] = (__bf16)fast_tanh(fmaf(Q1v, wa0.x, fmaf(Q2v, wb0.x, bb0.x)));    \
    F[1] = (__bf16)fast_tanh(fmaf(Q1v, wa0.y, fmaf(Q2v, wb0.y, bb0.y)));    \
    F[2] = (__bf16)fast_tanh(fmaf(Q1v, wa0.z, fmaf(Q2v, wb0.z, bb0.z)));    \
    F[3] = (__bf16)fast_tanh(fmaf(Q1v, wa0.w, fmaf(Q2v, wb0.w, bb0.w)));    \
    F[4] = (__bf16)fast_tanh(fmaf(Q1v, wa1.x, fmaf(Q2v, wb1.x, bb1.x)));    \
    F[5] = (__bf16)fast_tanh(fmaf(Q1v, wa1.y, fmaf(Q2v, wb1.y, bb1.y)));    \
    F[6] = (__bf16)fast_tanh(fmaf(Q1v, wa1.z, fmaf(Q2v, wb1.z, bb1.z)));    \
    F[7] = (__bf16)fast_tanh(fmaf(Q1v, wa1.w, fmaf(Q2v, wb1.w, bb1.w)));

// layer-1 half fragment for all 4 tiles; one set of weight loads
#define L1HALF4(FA, FB, FC, FD, K0)                                         \
    do {                                                                    \
        const float4 wa0 = *(const float4*)(W1 + (K0));                     \
        const float4 wa1 = *(const float4*)(W1 + (K0) + 4);                 \
        const float4 wb0 = *(const float4*)(W1 + HID + (K0));               \
        const float4 wb1 = *(const float4*)(W1 + HID + (K0) + 4);           \
        const float4 bb0 = *(const float4*)(b1 + (K0));                     \
        const float4 bb1 = *(const float4*)(b1 + (K0) + 4);                 \
        TANH8(FA, q1A, q2A)                                                 \
        TANH8(FB, q1B, q2B)                                                 \
        TANH8(FC, q1C, q2C)                                                 \
        TANH8(FD, q1D, q2D)                                                 \
    } while (0)

#define MFMA __builtin_amdgcn_mfma_f32_16x16x32_bf16

// GEMM1 m-tile: two weight frags feed all 4 tiles
#define G1MT(MT, ZA, ZB, ZC, ZD)                                            \
    do {                                                                    \
        const bf16x8 wf0 = *(const bf16x8*)(w2t + (MT) * 1024);             \
        ZA = MFMA(wf0, a10A, ZA, 0, 0, 0);                                  \
        ZB = MFMA(wf0, a10B, ZB, 0, 0, 0);                                  \
        ZC = MFMA(wf0, a10C, ZC, 0, 0, 0);                                  \
        ZD = MFMA(wf0, a10D, ZD, 0, 0, 0);                                  \
        const bf16x8 wf1 = *(const bf16x8*)(w2t + (MT) * 1024 + 32);        \
        ZA = MFMA(wf1, a11A, ZA, 0, 0, 0);                                  \
        ZB = MFMA(wf1, a11B, ZB, 0, 0, 0);                                  \
        ZC = MFMA(wf1, a11C, ZC, 0, 0, 0);                                  \
        ZD = MFMA(wf1, a11D, ZD, 0, 0, 0);                                  \
    } while (0)

// tanh + V partial + g2 pack/store, one tile (w3v in scope)
#define H2ONE(Z, VP, GBUF, MT)                                                      \
    do {                                                                            \
        float h, g0_, g1_, g2_, g3_;                                                \
        h = fast_tanh(Z[0]); VP = fmaf(h, w3v.x, VP); g0_ = w3v.x * (1.0f - h * h); \
        h = fast_tanh(Z[1]); VP = fmaf(h, w3v.y, VP); g1_ = w3v.y * (1.0f - h * h); \
        h = fast_tanh(Z[2]); VP = fmaf(h, w3v.z, VP); g2_ = w3v.z * (1.0f - h * h); \
        h = fast_tanh(Z[3]); VP = fmaf(h, w3v.w, VP); g3_ = w3v.w * (1.0f - h * h); \
        bf16x4 gv = {(__bf16)g0_, (__bf16)g1_, (__bf16)g2_, (__bf16)g3_};           \
        *(bf16x4*)((GBUF) + rowbase + ((16 * (MT) + 4 * hi) ^ swz)) = gv;           \
    } while (0)

#define H2MT4(MT, ZA, ZB, ZC, ZD)                                           \
    do {                                                                    \
        const float4 w3v = *(const float4*)(W3 + 16 * (MT) + 4 * hi);       \
        H2ONE(ZA, vpA, g2A, MT);                                            \
        H2ONE(ZB, vpB, g2B, MT);                                            \
        H2ONE(ZC, vpC, g2C, MT);                                            \
        H2ONE(ZD, vpD, g2D, MT);                                            \
    } while (0)

// GEMM2 m-tile
#define G2MT(MT, RA, RB, RC, RD)                                            \
    do {                                                                    \
        const bf16x8 wf0 = *(const bf16x8*)(w2b + (MT) * 1024);             \
        RA = MFMA(wf0, a20A, RA, 0, 0, 0);                                  \
        RB = MFMA(wf0, a20B, RB, 0, 0, 0);                                  \
        RC = MFMA(wf0, a20C, RC, 0, 0, 0);                                  \
        RD = MFMA(wf0, a20D, RD, 0, 0, 0);                                  \
        const bf16x8 wf1 = *(const bf16x8*)(w2b + (MT) * 1024 + 32);        \
        RA = MFMA(wf1, a21A, RA, 0, 0, 0);                                  \
        RB = MFMA(wf1, a21B, RB, 0, 0, 0);                                  \
        RC = MFMA(wf1, a21C, RC, 0, 0, 0);                                  \
        RD = MFMA(wf1, a21D, RD, 0, 0, 0);                                  \
    } while (0)

// backward one tile at m-tile MT (w1av,w1bv,b1v in scope); h1 recomputed
#define DVONE(R, Q1v, Q2v, D1, D2)                                                            \
    do {                                                                                      \
        float hf, gi;                                                                         \
        hf = fast_tanh(fmaf(Q1v, w1av.x, fmaf(Q2v, w1bv.x, b1v.x)));                          \
        gi = (1.0f - hf * hf) * R[0]; D1 = fmaf(w1av.x, gi, D1); D2 = fmaf(w1bv.x, gi, D2);   \
        hf = fast_tanh(fmaf(Q1v, w1av.y, fmaf(Q2v, w1bv.y, b1v.y)));                          \
        gi = (1.0f - hf * hf) * R[1]; D1 = fmaf(w1av.y, gi, D1); D2 = fmaf(w1bv.y, gi, D2);   \
        hf = fast_tanh(fmaf(Q1v, w1av.z, fmaf(Q2v, w1bv.z, b1v.z)));                          \
        gi = (1.0f - hf * hf) * R[2]; D1 = fmaf(w1av.z, gi, D1); D2 = fmaf(w1bv.z, gi, D2);   \
        hf = fast_tanh(fmaf(Q1v, w1av.w, fmaf(Q2v, w1bv.w, b1v.w)));                          \
        gi = (1.0f - hf * hf) * R[3]; D1 = fmaf(w1av.w, gi, D1); D2 = fmaf(w1bv.w, gi, D2);   \
    } while (0)

#define DVMT4(MT, RA, RB, RC, RD)                                           \
    do {                                                                    \
        const float4 w1av = *(const float4*)(W1 + 16 * (MT) + 4 * hi);      \
        const float4 w1bv = *(const float4*)(W1 + HID + 16 * (MT) + 4 * hi);\
        const float4 b1v  = *(const float4*)(b1 + 16 * (MT) + 4 * hi);      \
        DVONE(RA, q1A, q2A, d1A, d2A);                                      \
        DVONE(RB, q1B, q2B, d1B, d2B);                                      \
        DVONE(RC, q1C, q2C, d1C, d2C);                                      \
        DVONE(RD, q1D, q2D, d1D, d2D);                                      \
    } while (0)

#define RED2(V) V += __shfl_xor(V, 16, 64); V += __shfl_xor(V, 32, 64);

#define SEL4(A, B, C, D) ((hi == 0) ? (A) : (hi == 1) ? (B) : (hi == 2) ? (C) : (D))

// ---- main: FOUR interleaved 16-row tiles per wave; physics on all 64 lanes ----
__global__ __launch_bounds__(256, 3) void pend_kernel(
    const float4* __restrict__ x,
    const float* __restrict__ W1, const float* __restrict__ b1,
    const __bf16* __restrict__ W2bf, const __bf16* __restrict__ W2Tbf,
    const float* __restrict__ b2,
    const float* __restrict__ W3, const float* __restrict__ b3,
    const float* __restrict__ Tp, const float* __restrict__ edes_p,
    float4* __restrict__ out, int n)
{
    __shared__ __align__(16) __bf16 lds[4 * 4096];  // per wave: g2 x 4 tiles (2 KB each)
    const int tid = threadIdx.x;
    const int w = tid >> 6, l = tid & 63;
    const int lo = l & 15, hi = l >> 4;
    __bf16* g2A = lds + w * 4096;
    __bf16* g2B = g2A + 1024;
    __bf16* g2C = g2B + 1024;
    __bf16* g2D = g2C + 1024;

    const float E_des = edes_p[0];
    const float Tabs = fabsf(Tp[0]);
    const float b3c = b3[0];

    const int base = blockIdx.x * 256 + w * 64;   // 64 rows per wave
    int eA = base + lo;       if (eA >= n) eA = n - 1;
    int eB = base + 16 + lo;  if (eB >= n) eB = n - 1;
    int eC = base + 32 + lo;  if (eC >= n) eC = n - 1;
    int eD = base + 48 + lo;  if (eD >= n) eD = n - 1;
    const float4 xvA = x[eA];
    const float4 xvB = x[eB];
    const float4 xvC = x[eC];
    const float4 xvD = x[eD];
    const float q1A = xvA.x, q2A = xvA.y, p1A = xvA.z, p2A = xvA.w;
    const float q1B = xvB.x, q2B = xvB.y, p1B = xvB.z, p2B = xvB.w;
    const float q1C = xvC.x, q2C = xvC.y, p1C = xvC.z, p2C = xvC.w;
    const float q1D = xvD.x, q2D = xvD.y, p1D = xvD.z, p2D = xvD.w;

    const int swz = (lo & 7) << 3;          // XOR swizzle on j (bits 3..5)
    const int rowbase = lo * HID;

    // ---- layer-1 for 4 tiles (shared weight loads) ----
    bf16x8 a10A, a11A, a10B, a11B, a10C, a11C, a10D, a11D;
    L1HALF4(a10A, a10B, a10C, a10D, 8 * hi);
    L1HALF4(a11A, a11B, a11C, a11D, 32 + 8 * hi);

    const __bf16* w2t = W2Tbf + lo * HID + 8 * hi;   // + mt*1024 (+32 for kh=1)
    const __bf16* w2b = W2bf  + lo * HID + 8 * hi;

    // ---- GEMM1 (swapped): Z^T = W2^T @ H1^T, 4 tiles ----
    const float4 b2v0 = *(const float4*)(b2 + 4 * hi);
    const float4 b2v1 = *(const float4*)(b2 + 16 + 4 * hi);
    const float4 b2v2 = *(const float4*)(b2 + 32 + 4 * hi);
    const float4 b2v3 = *(const float4*)(b2 + 48 + 4 * hi);
    f32x4 zA0 = {b2v0.x, b2v0.y, b2v0.z, b2v0.w};
    f32x4 zA1 = {b2v1.x, b2v1.y, b2v1.z, b2v1.w};
    f32x4 zA2 = {b2v2.x, b2v2.y, b2v2.z, b2v2.w};
    f32x4 zA3 = {b2v3.x, b2v3.y, b2v3.z, b2v3.w};
    f32x4 zB0 = zA0, zB1 = zA1, zB2 = zA2, zB3 = zA3;
    f32x4 zC0 = zA0, zC1 = zA1, zC2 = zA2, zC3 = zA3;
    f32x4 zD0 = zA0, zD1 = zA1, zD2 = zA2, zD3 = zA3;
    G1MT(0, zA0, zB0, zC0, zD0);
    G1MT(1, zA1, zB1, zC1, zD1);
    G1MT(2, zA2, zB2, zC2, zD2);
    G1MT(3, zA3, zB3, zC3, zD3);

    // ---- h2/V/g2 (lane-local rows) ----
    float vpA = 0.0f, vpB = 0.0f, vpC = 0.0f, vpD = 0.0f;
    H2MT4(0, zA0, zB0, zC0, zD0);
    H2MT4(1, zA1, zB1, zC1, zD1);
    H2MT4(2, zA2, zB2, zC2, zD2);
    H2MT4(3, zA3, zB3, zC3, zD3);

    // ---- GEMM2 (swapped): R^T = W2 @ G2^T, 4 tiles ----
    const bf16x8 a20A = *(const bf16x8*)(g2A + rowbase + ((8 * hi) ^ swz));
    const bf16x8 a21A = *(const bf16x8*)(g2A + rowbase + ((32 + 8 * hi) ^ swz));
    const bf16x8 a20B = *(const bf16x8*)(g2B + rowbase + ((8 * hi) ^ swz));
    const bf16x8 a21B = *(const bf16x8*)(g2B + rowbase + ((32 + 8 * hi) ^ swz));
    const bf16x8 a20C = *(const bf16x8*)(g2C + rowbase + ((8 * hi) ^ swz));
    const bf16x8 a21C = *(const bf16x8*)(g2C + rowbase + ((32 + 8 * hi) ^ swz));
    const bf16x8 a20D = *(const bf16x8*)(g2D + rowbase + ((8 * hi) ^ swz));
    const bf16x8 a21D = *(const bf16x8*)(g2D + rowbase + ((32 + 8 * hi) ^ swz));
    f32x4 rA0 = {0.f, 0.f, 0.f, 0.f}, rA1 = rA0, rA2 = rA0, rA3 = rA0;
    f32x4 rB0 = rA0, rB1 = rA0, rB2 = rA0, rB3 = rA0;
    f32x4 rC0 = rA0, rC1 = rA0, rC2 = rA0, rC3 = rA0;
    f32x4 rD0 = rA0, rD1 = rA0, rD2 = rA0, rD3 = rA0;
    G2MT(0, rA0, rB0, rC0, rD0);
    G2MT(1, rA1, rB1, rC1, rD1);
    G2MT(2, rA2, rB2, rC2, rD2);
    G2MT(3, rA3, rB3, rC3, rD3);

    // ---- backward partials (h1 recomputed, shared weight loads) ----
    float d1A = 0.f, d2A = 0.f, d1B = 0.f, d2B = 0.f;
    float d1C = 0.f, d2C = 0.f, d1D = 0.f, d2D = 0.f;
    DVMT4(0, rA0, rB0, rC0, rD0);
    DVMT4(1, rA1, rB1, rC1, rD1);
    DVMT4(2, rA2, rB2, rC2, rD2);
    DVMT4(3, rA3, rB3, rC3, rD3);

    // ---- reduce over hi-groups; each lane then owns row base + l (tile = hi) ----
    RED2(vpA) RED2(vpB) RED2(vpC) RED2(vpD)
    RED2(d1A) RED2(d1B) RED2(d1C) RED2(d1D)
    RED2(d2A) RED2(d2B) RED2(d2C) RED2(d2D)

    const float V    = SEL4(vpA, vpB, vpC, vpD) + b3c;
    const float dVq1 = SEL4(d1A, d1B, d1C, d1D);
    const float dVq2 = SEL4(d2A, d2B, d2C, d2D);
    const float q1 = SEL4(q1A, q1B, q1C, q1D);
    const float q2 = SEL4(q2A, q2B, q2C, q2D);
    const float p1 = SEL4(p1A, p1B, p1C, p1D);
    const float p2 = SEL4(p2A, p2B, p2C, p2D);

    // ---- physics, once per lane (row = base + l) ----
    float s2q, c2q, s1q, c1q;
    __sincosf(q2, &s2q, &c2q);
    __sincosf(q1, &s1q, &c1q);
    const float s12 = s1q * c2q + c1q * s2q;
    const float c12 = c1q * c2q - s1q * s2q;

    const float cc = c2q, s = s2q;
    const float DEN = 2.0f - cc * cc;        // == 1 + s^2
    const float rDEN = __builtin_amdgcn_rcpf(DEN);
    const float cp1 = cc + 1.0f;

    const float quad = (p1 * p1 - 2.0f * cp1 * p1 * p2 + (2.0f * cc + 3.0f) * p2 * p2) * rDEN;
    const float kin = 0.5f * quad;
    const float dqa = 1.57079632679489662f - q2;
    const float pot = -9.81f * (c12 + 2.0f * c1q) + 0.5f * dqa * dqa;
    const float E = pot + kin + V;

    const float fac = (quad > 0.0f) ? __builtin_amdgcn_rsqf(quad) : 1.0f;
    const float coef = E_des - E;
    const float u1 = -dVq1 + coef * p1 * fac;
    const float u2 = -dVq2 + coef * p2 * fac;

    const float dq1dt = (p1 - cp1 * p2) * rDEN;
    const float dq2dt = ((2.0f * cc + 3.0f) * p2 - cp1 * p1) * rDEN;
    const float dp1dt = -9.81f * (s12 + 2.0f * s1q) + u1;

    const float inner = -p2 * p2 * s * cp1 * (cc + 2.0f)
                + p1 * p2 * s * (fmaf(cc, cc, fmaf(2.0f, cc, 2.0f)))
                - cc * p1 * p1 * s
                + DEN * DEN * (fmaf(9.81f, s12, -0.5f * (3.14159265358979324f - 2.0f * q2)));
    const float dp2dt = -(inner * rDEN * rDEN) + u2;

    const int row = base + l;
    if (row < n) {
        float4 o;
        o.x = Tabs * dq1dt;
        o.y = Tabs * dq2dt;
        o.z = Tabs * dp1dt;
        o.w = Tabs * dp2dt;
        out[row] = o;
    }
}

extern "C" void kernel_launch(void* const* d_in, const int* in_sizes, int n_in,
                              void* d_out, int out_size, void* d_ws, size_t ws_size,
                              hipStream_t stream) {
    const float* x  = (const float*)d_in[0];
    // d_in[1] = t (unused)
    const float* W1 = (const float*)d_in[2];
    const float* b1 = (const float*)d_in[3];
    const float* W2 = (const float*)d_in[4];
    const float* b2 = (const float*)d_in[5];
    const float* W3 = (const float*)d_in[6];
    const float* b3 = (const float*)d_in[7];
    const float* Tp = (const float*)d_in[8];
    const float* x0 = (const float*)d_in[9];

    float* ws = (float*)d_ws;
    float* edes = ws;                                   // 1 float (+ padding to 64B)
    __bf16* W2bf  = (__bf16*)(ws + 16);                 // 4096 bf16 = 8 KB
    __bf16* W2Tbf = W2bf + HID * HID;                   // 4096 bf16 = 8 KB

    prep_kernel<<<1, 256, 0, stream>>>(W1, b1, W2, b2, W3, b3, x0, edes, W2bf, W2Tbf);

    int n = in_sizes[0] / 4;  // 500000
    int blocks = (n + 255) / 256;  // 256 rows per block (4 waves x 4 tiles x 16) -> 1954
    pend_kernel<<<blocks, 256, 0, stream>>>((const float4*)x, W1, b1, W2bf, W2Tbf,
                                            b2, W3, b3, Tp, edes, (float4*)d_out, n);
}

// Round 13
// 49.107 us; speedup vs baseline: 1.9289x; 1.0486x over previous
//
#include <hip/hip_runtime.h>
#include <math.h>

#define HID 64

typedef __attribute__((ext_vector_type(4))) float f32x4;
typedef __attribute__((ext_vector_type(8))) __bf16 bf16x8;
typedef __attribute__((ext_vector_type(4))) __bf16 bf16x4;

__device__ __forceinline__ float fast_tanh(float x) {
    // tanh(x) = 1 - 2/(exp(2x)+1); exp overflow -> inf -> rcp -> 0 -> 1 (correct)
    float e = __expf(2.0f * x);
    return 1.0f - 2.0f * __builtin_amdgcn_rcpf(e + 1.0f);
}

// ---- prep: bf16 weight tables (W2, W2^T) + E_des, all into d_ws ----
__global__ void prep_kernel(const float* __restrict__ W1, const float* __restrict__ b1,
                            const float* __restrict__ W2, const float* __restrict__ b2,
                            const float* __restrict__ W3, const float* __restrict__ b3,
                            const float* __restrict__ x0, float* __restrict__ edes_out,
                            __bf16* __restrict__ W2bf, __bf16* __restrict__ W2Tbf) {
    int tid = threadIdx.x;  // 256 threads
    for (int idx = tid; idx < HID * HID; idx += 256) {
        W2bf[idx] = (__bf16)W2[idx];
        int r = idx >> 6, c = idx & 63;
        W2Tbf[idx] = (__bf16)W2[c * HID + r];
    }
    if (tid < 64) {
        int j = tid;
        float q1 = x0[0], q2 = x0[1], p1 = x0[2], p2 = x0[3];
        float h1j = fast_tanh(fmaf(q1, W1[j], fmaf(q2, W1[HID + j], b1[j])));
        float z = b2[j];
#pragma unroll 1
        for (int i = 0; i < HID; i++) {
            float hi = __shfl(h1j, i, 64);
            z = fmaf(hi, W2[i * HID + j], z);
        }
        float h2 = fast_tanh(z);
        float v = h2 * W3[j];
#pragma unroll
        for (int off = 32; off; off >>= 1) v += __shfl_xor(v, off, 64);
        if (j == 0) {
            float V = v + b3[0];
            float s, c;
            __sincosf(q2, &s, &c);
            float DEN = 2.0f - c * c;
            float rDEN = __builtin_amdgcn_rcpf(DEN);
            float quad = (p1 * p1 - 2.0f * (c + 1.0f) * p1 * p2 + (2.0f * c + 3.0f) * p2 * p2) * rDEN;
            float kin = 0.5f * quad;
            float s1, c1;
            __sincosf(q1, &s1, &c1);
            float c12 = c1 * c - s1 * s;
            float dq = 1.57079632679489662f - q2;
            float pot = -9.81f * (c12 + 2.0f * c1) + 0.5f * dq * dq;
            edes_out[0] = pot + kin + V;
        }
    }
}

// 8 tanh into fragment F for one tile (wa0..bb1 in scope)
#define TANH8(F, Q1v, Q2v)                                                  \
    F[0] = (__bf16)fast_tanh(fmaf(Q1v, wa0.x, fmaf(Q2v, wb0.x, bb0.x)));    \
    F[1] = (__bf16)fast_tanh(fmaf(Q1v, wa0.y, fmaf(Q2v, wb0.y, bb0.y)));    \
    F[2] = (__bf16)fast_tanh(fmaf(Q1v, wa0.z, fmaf(Q2v, wb0.z, bb0.z)));    \
    F[3] = (__bf16)fast_tanh(fmaf(Q1v, wa0.w, fmaf(Q2v, wb0.w, bb0.w)));    \
    F[4] = (__bf16)fast_tanh(fmaf(Q1v, wa1.x, fmaf(Q2v, wb1.x, bb1.x)));    \
    F[5] = (__bf16)fast_tanh(fmaf(Q1v, wa1.y, fmaf(Q2v, wb1.y, bb1.y)));    \
    F[6] = (__bf16)fast_tanh(fmaf(Q1v, wa1.z, fmaf(Q2v, wb1.z, bb1.z)));    \
    F[7] = (__bf16)fast_tanh(fmaf(Q1v, wa1.w, fmaf(Q2v, wb1.w, bb1.w)));

// layer-1 half fragment for all 4 tiles; one set of weight loads
#define L1HALF4(FA, FB, FC, FD, K0)                                         \
    do {                                                                    \
        const float4 wa0 = *(const float4*)(W1 + (K0));                     \
        const float4 wa1 = *(const float4*)(W1 + (K0) + 4);                 \
        const float4 wb0 = *(const float4*)(W1 + HID + (K0));               \
        const float4 wb1 = *(const float4*)(W1 + HID + (K0) + 4);           \
        const float4 bb0 = *(const float4*)(b1 + (K0));                     \
        const float4 bb1 = *(const float4*)(b1 + (K0) + 4);                 \
        TANH8(FA, q1A, q2A)                                                 \
        TANH8(FB, q1B, q2B)                                                 \
        TANH8(FC, q1C, q2C)                                                 \
        TANH8(FD, q1D, q2D)                                                 \
    } while (0)

#define MFMA __builtin_amdgcn_mfma_f32_16x16x32_bf16

// tanh + V partial + g2 pack/store, one tile (w3v in scope)
#define H2ONE(Z, VP, GBUF, MT)                                                      \
    do {                                                                            \
        float h, g0_, g1_, g2_, g3_;                                                \
        h = fast_tanh(Z[0]); VP = fmaf(h, w3v.x, VP); g0_ = w3v.x * (1.0f - h * h); \
        h = fast_tanh(Z[1]); VP = fmaf(h, w3v.y, VP); g1_ = w3v.y * (1.0f - h * h); \
        h = fast_tanh(Z[2]); VP = fmaf(h, w3v.z, VP); g2_ = w3v.z * (1.0f - h * h); \
        h = fast_tanh(Z[3]); VP = fmaf(h, w3v.w, VP); g3_ = w3v.w * (1.0f - h * h); \
        bf16x4 gv = {(__bf16)g0_, (__bf16)g1_, (__bf16)g2_, (__bf16)g3_};           \
        *(bf16x4*)((GBUF) + rowbase + ((16 * (MT) + 4 * hi) ^ swz)) = gv;           \
    } while (0)

// one forward m-tile: bias init + GEMM1 + tanh/V/g2 for all 4 tiles; accs die here
#define FWDMT(MT)                                                           \
    do {                                                                    \
        const float4 b2v = *(const float4*)(b2 + 16 * (MT) + 4 * hi);       \
        f32x4 zA = {b2v.x, b2v.y, b2v.z, b2v.w};                            \
        f32x4 zB = zA, zC = zA, zD = zA;                                    \
        const bf16x8 wf0 = *(const bf16x8*)(w2t + (MT) * 1024);             \
        zA = MFMA(wf0, a10A, zA, 0, 0, 0);                                  \
        zB = MFMA(wf0, a10B, zB, 0, 0, 0);                                  \
        zC = MFMA(wf0, a10C, zC, 0, 0, 0);                                  \
        zD = MFMA(wf0, a10D, zD, 0, 0, 0);                                  \
        const bf16x8 wf1 = *(const bf16x8*)(w2t + (MT) * 1024 + 32);        \
        zA = MFMA(wf1, a11A, zA, 0, 0, 0);                                  \
        zB = MFMA(wf1, a11B, zB, 0, 0, 0);                                  \
        zC = MFMA(wf1, a11C, zC, 0, 0, 0);                                  \
        zD = MFMA(wf1, a11D, zD, 0, 0, 0);                                  \
        const float4 w3v = *(const float4*)(W3 + 16 * (MT) + 4 * hi);       \
        H2ONE(zA, vpA, g2A, MT);                                            \
        H2ONE(zB, vpB, g2B, MT);                                            \
        H2ONE(zC, vpC, g2C, MT);                                            \
        H2ONE(zD, vpD, g2D, MT);                                            \
    } while (0)

// backward one tile at m-tile MT (w1av,w1bv,b1v in scope); h1 recomputed
#define DVONE(R, Q1v, Q2v, D1, D2)                                                            \
    do {                                                                                      \
        float hf, gi;                                                                         \
        hf = fast_tanh(fmaf(Q1v, w1av.x, fmaf(Q2v, w1bv.x, b1v.x)));                          \
        gi = (1.0f - hf * hf) * R[0]; D1 = fmaf(w1av.x, gi, D1); D2 = fmaf(w1bv.x, gi, D2);   \
        hf = fast_tanh(fmaf(Q1v, w1av.y, fmaf(Q2v, w1bv.y, b1v.y)));                          \
        gi = (1.0f - hf * hf) * R[1]; D1 = fmaf(w1av.y, gi, D1); D2 = fmaf(w1bv.y, gi, D2);   \
        hf = fast_tanh(fmaf(Q1v, w1av.z, fmaf(Q2v, w1bv.z, b1v.z)));                          \
        gi = (1.0f - hf * hf) * R[2]; D1 = fmaf(w1av.z, gi, D1); D2 = fmaf(w1bv.z, gi, D2);   \
        hf = fast_tanh(fmaf(Q1v, w1av.w, fmaf(Q2v, w1bv.w, b1v.w)));                          \
        gi = (1.0f - hf * hf) * R[3]; D1 = fmaf(w1av.w, gi, D1); D2 = fmaf(w1bv.w, gi, D2);   \
    } while (0)

// one backward m-tile: GEMM2 + mask/dV for all 4 tiles; accs die here
#define BWDMT(MT)                                                           \
    do {                                                                    \
        f32x4 rA = {0.f, 0.f, 0.f, 0.f};                                    \
        f32x4 rB = rA, rC = rA, rD = rA;                                    \
        const bf16x8 wf0 = *(const bf16x8*)(w2b + (MT) * 1024);             \
        rA = MFMA(wf0, a20A, rA, 0, 0, 0);                                  \
        rB = MFMA(wf0, a20B, rB, 0, 0, 0);                                  \
        rC = MFMA(wf0, a20C, rC, 0, 0, 0);                                  \
        rD = MFMA(wf0, a20D, rD, 0, 0, 0);                                  \
        const bf16x8 wf1 = *(const bf16x8*)(w2b + (MT) * 1024 + 32);        \
        rA = MFMA(wf1, a21A, rA, 0, 0, 0);                                  \
        rB = MFMA(wf1, a21B, rB, 0, 0, 0);                                  \
        rC = MFMA(wf1, a21C, rC, 0, 0, 0);                                  \
        rD = MFMA(wf1, a21D, rD, 0, 0, 0);                                  \
        const float4 w1av = *(const float4*)(W1 + 16 * (MT) + 4 * hi);      \
        const float4 w1bv = *(const float4*)(W1 + HID + 16 * (MT) + 4 * hi);\
        const float4 b1v  = *(const float4*)(b1 + 16 * (MT) + 4 * hi);      \
        DVONE(rA, q1A, q2A, d1A, d2A);                                      \
        DVONE(rB, q1B, q2B, d1B, d2B);                                      \
        DVONE(rC, q1C, q2C, d1C, d2C);                                      \
        DVONE(rD, q1D, q2D, d1D, d2D);                                      \
    } while (0)

#define RED2(V) V += __shfl_xor(V, 16, 64); V += __shfl_xor(V, 32, 64);

#define SEL4(A, B, C, D) ((hi == 0) ? (A) : (hi == 1) ? (B) : (hi == 2) ? (C) : (D))

// ---- main: FOUR interleaved 16-row tiles per wave; per-m-tile acc lifetimes ----
__global__ __launch_bounds__(256, 4) void pend_kernel(
    const float4* __restrict__ x,
    const float* __restrict__ W1, const float* __restrict__ b1,
    const __bf16* __restrict__ W2bf, const __bf16* __restrict__ W2Tbf,
    const float* __restrict__ b2,
    const float* __restrict__ W3, const float* __restrict__ b3,
    const float* __restrict__ Tp, const float* __restrict__ edes_p,
    float4* __restrict__ out, int n)
{
    __shared__ __align__(16) __bf16 lds[4 * 4096];  // per wave: g2 x 4 tiles (2 KB each)
    const int tid = threadIdx.x;
    const int w = tid >> 6, l = tid & 63;
    const int lo = l & 15, hi = l >> 4;
    __bf16* g2A = lds + w * 4096;
    __bf16* g2B = g2A + 1024;
    __bf16* g2C = g2B + 1024;
    __bf16* g2D = g2C + 1024;

    const float E_des = edes_p[0];
    const float Tabs = fabsf(Tp[0]);
    const float b3c = b3[0];

    const int base = blockIdx.x * 256 + w * 64;   // 64 rows per wave
    int eA = base + lo;       if (eA >= n) eA = n - 1;
    int eB = base + 16 + lo;  if (eB >= n) eB = n - 1;
    int eC = base + 32 + lo;  if (eC >= n) eC = n - 1;
    int eD = base + 48 + lo;  if (eD >= n) eD = n - 1;
    const float4 xvA = x[eA];
    const float4 xvB = x[eB];
    const float4 xvC = x[eC];
    const float4 xvD = x[eD];
    const float q1A = xvA.x, q2A = xvA.y, p1A = xvA.z, p2A = xvA.w;
    const float q1B = xvB.x, q2B = xvB.y, p1B = xvB.z, p2B = xvB.w;
    const float q1C = xvC.x, q2C = xvC.y, p1C = xvC.z, p2C = xvC.w;
    const float q1D = xvD.x, q2D = xvD.y, p1D = xvD.z, p2D = xvD.w;

    const int swz = (lo & 7) << 3;          // XOR swizzle on j (bits 3..5)
    const int rowbase = lo * HID;

    // ---- layer-1 for 4 tiles (shared weight loads) ----
    bf16x8 a10A, a11A, a10B, a11B, a10C, a11C, a10D, a11D;
    L1HALF4(a10A, a10B, a10C, a10D, 8 * hi);
    L1HALF4(a11A, a11B, a11C, a11D, 32 + 8 * hi);

    const __bf16* w2t = W2Tbf + lo * HID + 8 * hi;   // + mt*1024 (+32 for kh=1)
    const __bf16* w2b = W2bf  + lo * HID + 8 * hi;

    // ---- forward: GEMM1 + h2/V/g2, one m-tile at a time (short acc lifetimes) ----
    float vpA = 0.0f, vpB = 0.0f, vpC = 0.0f, vpD = 0.0f;
    FWDMT(0);
    FWDMT(1);
    FWDMT(2);
    FWDMT(3);

    // ---- GEMM2 A-fragments from LDS (all g2 writes precede these reads, same wave) ----
    const bf16x8 a20A = *(const bf16x8*)(g2A + rowbase + ((8 * hi) ^ swz));
    const bf16x8 a21A = *(const bf16x8*)(g2A + rowbase + ((32 + 8 * hi) ^ swz));
    const bf16x8 a20B = *(const bf16x8*)(g2B + rowbase + ((8 * hi) ^ swz));
    const bf16x8 a21B = *(const bf16x8*)(g2B + rowbase + ((32 + 8 * hi) ^ swz));
    const bf16x8 a20C = *(const bf16x8*)(g2C + rowbase + ((8 * hi) ^ swz));
    const bf16x8 a21C = *(const bf16x8*)(g2C + rowbase + ((32 + 8 * hi) ^ swz));
    const bf16x8 a20D = *(const bf16x8*)(g2D + rowbase + ((8 * hi) ^ swz));
    const bf16x8 a21D = *(const bf16x8*)(g2D + rowbase + ((32 + 8 * hi) ^ swz));

    // ---- backward: GEMM2 + mask/dV, one m-tile at a time ----
    float d1A = 0.f, d2A = 0.f, d1B = 0.f, d2B = 0.f;
    float d1C = 0.f, d2C = 0.f, d1D = 0.f, d2D = 0.f;
    BWDMT(0);
    BWDMT(1);
    BWDMT(2);
    BWDMT(3);

    // ---- reduce over hi-groups; each lane then owns row base + l (tile = hi) ----
    RED2(vpA) RED2(vpB) RED2(vpC) RED2(vpD)
    RED2(d1A) RED2(d1B) RED2(d1C) RED2(d1D)
    RED2(d2A) RED2(d2B) RED2(d2C) RED2(d2D)

    const float V    = SEL4(vpA, vpB, vpC, vpD) + b3c;
    const float dVq1 = SEL4(d1A, d1B, d1C, d1D);
    const float dVq2 = SEL4(d2A, d2B, d2C, d2D);
    const float q1 = SEL4(q1A, q1B, q1C, q1D);
    const float q2 = SEL4(q2A, q2B, q2C, q2D);
    const float p1 = SEL4(p1A, p1B, p1C, p1D);
    const float p2 = SEL4(p2A, p2B, p2C, p2D);

    // ---- physics, once per lane (row = base + l) ----
    float s2q, c2q, s1q, c1q;
    __sincosf(q2, &s2q, &c2q);
    __sincosf(q1, &s1q, &c1q);
    const float s12 = s1q * c2q + c1q * s2q;
    const float c12 = c1q * c2q - s1q * s2q;

    const float cc = c2q, s = s2q;
    const float DEN = 2.0f - cc * cc;        // == 1 + s^2
    const float rDEN = __builtin_amdgcn_rcpf(DEN);
    const float cp1 = cc + 1.0f;

    const float quad = (p1 * p1 - 2.0f * cp1 * p1 * p2 + (2.0f * cc + 3.0f) * p2 * p2) * rDEN;
    const float kin = 0.5f * quad;
    const float dqa = 1.57079632679489662f - q2;
    const float pot = -9.81f * (c12 + 2.0f * c1q) + 0.5f * dqa * dqa;
    const float E = pot + kin + V;

    const float fac = (quad > 0.0f) ? __builtin_amdgcn_rsqf(quad) : 1.0f;
    const float coef = E_des - E;
    const float u1 = -dVq1 + coef * p1 * fac;
    const float u2 = -dVq2 + coef * p2 * fac;

    const float dq1dt = (p1 - cp1 * p2) * rDEN;
    const float dq2dt = ((2.0f * cc + 3.0f) * p2 - cp1 * p1) * rDEN;
    const float dp1dt = -9.81f * (s12 + 2.0f * s1q) + u1;

    const float inner = -p2 * p2 * s * cp1 * (cc + 2.0f)
                + p1 * p2 * s * (fmaf(cc, cc, fmaf(2.0f, cc, 2.0f)))
                - cc * p1 * p1 * s
                + DEN * DEN * (fmaf(9.81f, s12, -0.5f * (3.14159265358979324f - 2.0f * q2)));
    const float dp2dt = -(inner * rDEN * rDEN) + u2;

    const int row = base + l;
    if (row < n) {
        float4 o;
        o.x = Tabs * dq1dt;
        o.y = Tabs * dq2dt;
        o.z = Tabs * dp1dt;
        o.w = Tabs * dp2dt;
        out[row] = o;
    }
}

extern "C" void kernel_launch(void* const* d_in, const int* in_sizes, int n_in,
                              void* d_out, int out_size, void* d_ws, size_t ws_size,
                              hipStream_t stream) {
    const float* x  = (const float*)d_in[0];
    // d_in[1] = t (unused)
    const float* W1 = (const float*)d_in[2];
    const float* b1 = (const float*)d_in[3];
    const float* W2 = (const float*)d_in[4];
    const float* b2 = (const float*)d_in[5];
    const float* W3 = (const float*)d_in[6];
    const float* b3 = (const float*)d_in[7];
    const float* Tp = (const float*)d_in[8];
    const float* x0 = (const float*)d_in[9];

    float* ws = (float*)d_ws;
    float* edes = ws;                                   // 1 float (+ padding to 64B)
    __bf16* W2bf  = (__bf16*)(ws + 16);                 // 4096 bf16 = 8 KB
    __bf16* W2Tbf = W2bf + HID * HID;                   // 4096 bf16 = 8 KB

    prep_kernel<<<1, 256, 0, stream>>>(W1, b1, W2, b2, W3, b3, x0, edes, W2bf, W2Tbf);

    int n = in_sizes[0] / 4;  // 500000
    int blocks = (n + 255) / 256;  // 256 rows per block (4 waves x 4 tiles x 16) -> 1954
    pend_kernel<<<blocks, 256, 0, stream>>>((const float4*)x, W1, b1, W2bf, W2Tbf,
                                            b2, W3, b3, Tp, edes, (float4*)d_out, n);
}

// Round 14
// 44.478 us; speedup vs baseline: 2.1297x; 1.1041x over previous
//
#include <hip/hip_runtime.h>
#include <math.h>

#define HID 64

typedef __attribute__((ext_vector_type(4))) float f32x4;
typedef __attribute__((ext_vector_type(8))) __bf16 bf16x8;
typedef __attribute__((ext_vector_type(4))) __bf16 bf16x4;

__device__ __forceinline__ float fast_tanh(float x) {
    // tanh(x) = 1 - 2/(exp(2x)+1); exp overflow -> inf -> rcp -> 0 -> 1 (correct)
    float e = __expf(2.0f * x);
    return 1.0f - 2.0f * __builtin_amdgcn_rcpf(e + 1.0f);
}

// ---- prep: bf16 weight tables (W2, W2^T) + E_des, all into d_ws ----
__global__ void prep_kernel(const float* __restrict__ W1, const float* __restrict__ b1,
                            const float* __restrict__ W2, const float* __restrict__ b2,
                            const float* __restrict__ W3, const float* __restrict__ b3,
                            const float* __restrict__ x0, float* __restrict__ edes_out,
                            __bf16* __restrict__ W2bf, __bf16* __restrict__ W2Tbf) {
    int tid = threadIdx.x;  // 256 threads
    for (int idx = tid; idx < HID * HID; idx += 256) {
        W2bf[idx] = (__bf16)W2[idx];
        int r = idx >> 6, c = idx & 63;
        W2Tbf[idx] = (__bf16)W2[c * HID + r];
    }
    if (tid < 64) {
        int j = tid;
        float q1 = x0[0], q2 = x0[1], p1 = x0[2], p2 = x0[3];
        float h1j = fast_tanh(fmaf(q1, W1[j], fmaf(q2, W1[HID + j], b1[j])));
        float z = b2[j];
#pragma unroll 1
        for (int i = 0; i < HID; i++) {
            float hi = __shfl(h1j, i, 64);
            z = fmaf(hi, W2[i * HID + j], z);
        }
        float h2 = fast_tanh(z);
        float v = h2 * W3[j];
#pragma unroll
        for (int off = 32; off; off >>= 1) v += __shfl_xor(v, off, 64);
        if (j == 0) {
            float V = v + b3[0];
            float s, c;
            __sincosf(q2, &s, &c);
            float DEN = 2.0f - c * c;
            float rDEN = __builtin_amdgcn_rcpf(DEN);
            float quad = (p1 * p1 - 2.0f * (c + 1.0f) * p1 * p2 + (2.0f * c + 3.0f) * p2 * p2) * rDEN;
            float kin = 0.5f * quad;
            float s1, c1;
            __sincosf(q1, &s1, &c1);
            float c12 = c1 * c - s1 * s;
            float dq = 1.57079632679489662f - q2;
            float pot = -9.81f * (c12 + 2.0f * c1) + 0.5f * dq * dq;
            edes_out[0] = pot + kin + V;
        }
    }
}

// 8 tanh into fragment F + mask fragment M (wa0..bb1 in scope)
#define TANH8M(F, M, Q1v, Q2v)                                                                        \
    {                                                                                                 \
        float h;                                                                                      \
        h = fast_tanh(fmaf(Q1v, wa0.x, fmaf(Q2v, wb0.x, bb0.x))); F[0] = (__bf16)h; M[0] = (__bf16)fmaf(-h, h, 1.0f); \
        h = fast_tanh(fmaf(Q1v, wa0.y, fmaf(Q2v, wb0.y, bb0.y))); F[1] = (__bf16)h; M[1] = (__bf16)fmaf(-h, h, 1.0f); \
        h = fast_tanh(fmaf(Q1v, wa0.z, fmaf(Q2v, wb0.z, bb0.z))); F[2] = (__bf16)h; M[2] = (__bf16)fmaf(-h, h, 1.0f); \
        h = fast_tanh(fmaf(Q1v, wa0.w, fmaf(Q2v, wb0.w, bb0.w))); F[3] = (__bf16)h; M[3] = (__bf16)fmaf(-h, h, 1.0f); \
        h = fast_tanh(fmaf(Q1v, wa1.x, fmaf(Q2v, wb1.x, bb1.x))); F[4] = (__bf16)h; M[4] = (__bf16)fmaf(-h, h, 1.0f); \
        h = fast_tanh(fmaf(Q1v, wa1.y, fmaf(Q2v, wb1.y, bb1.y))); F[5] = (__bf16)h; M[5] = (__bf16)fmaf(-h, h, 1.0f); \
        h = fast_tanh(fmaf(Q1v, wa1.z, fmaf(Q2v, wb1.z, bb1.z))); F[6] = (__bf16)h; M[6] = (__bf16)fmaf(-h, h, 1.0f); \
        h = fast_tanh(fmaf(Q1v, wa1.w, fmaf(Q2v, wb1.w, bb1.w))); F[7] = (__bf16)h; M[7] = (__bf16)fmaf(-h, h, 1.0f); \
    }

// layer-1 half fragment + mask store for all 4 tiles; one set of weight loads
#define L1HALF4(FA, FB, FC, FD, K0)                                         \
    do {                                                                    \
        const float4 wa0 = *(const float4*)(W1 + (K0));                     \
        const float4 wa1 = *(const float4*)(W1 + (K0) + 4);                 \
        const float4 wb0 = *(const float4*)(W1 + HID + (K0));               \
        const float4 wb1 = *(const float4*)(W1 + HID + (K0) + 4);           \
        const float4 bb0 = *(const float4*)(b1 + (K0));                     \
        const float4 bb1 = *(const float4*)(b1 + (K0) + 4);                 \
        bf16x8 mA, mB, mC, mD;                                              \
        TANH8M(FA, mA, q1A, q2A)                                            \
        TANH8M(FB, mB, q1B, q2B)                                            \
        TANH8M(FC, mC, q1C, q2C)                                            \
        TANH8M(FD, mD, q1D, q2D)                                            \
        const int mo = rowbase + ((K0) ^ swz);                              \
        *(bf16x8*)(mkA + mo) = mA;                                          \
        *(bf16x8*)(mkB + mo) = mB;                                          \
        *(bf16x8*)(mkC + mo) = mC;                                          \
        *(bf16x8*)(mkD + mo) = mD;                                          \
    } while (0)

#define MFMA __builtin_amdgcn_mfma_f32_16x16x32_bf16

// tanh + V partial + g2 pack/store, one tile (w3v in scope)
#define H2ONE(Z, VP, GBUF, MT)                                                      \
    do {                                                                            \
        float h, g0_, g1_, g2_, g3_;                                                \
        h = fast_tanh(Z[0]); VP = fmaf(h, w3v.x, VP); g0_ = w3v.x * (1.0f - h * h); \
        h = fast_tanh(Z[1]); VP = fmaf(h, w3v.y, VP); g1_ = w3v.y * (1.0f - h * h); \
        h = fast_tanh(Z[2]); VP = fmaf(h, w3v.z, VP); g2_ = w3v.z * (1.0f - h * h); \
        h = fast_tanh(Z[3]); VP = fmaf(h, w3v.w, VP); g3_ = w3v.w * (1.0f - h * h); \
        bf16x4 gv = {(__bf16)g0_, (__bf16)g1_, (__bf16)g2_, (__bf16)g3_};           \
        *(bf16x4*)((GBUF) + rowbase + ((16 * (MT) + 4 * hi) ^ swz)) = gv;           \
    } while (0)

// one forward m-tile: bias init + GEMM1 + tanh/V/g2 for all 4 tiles; accs die here
#define FWDMT(MT)                                                           \
    do {                                                                    \
        const float4 b2v = *(const float4*)(b2 + 16 * (MT) + 4 * hi);       \
        f32x4 zA = {b2v.x, b2v.y, b2v.z, b2v.w};                            \
        f32x4 zB = zA, zC = zA, zD = zA;                                    \
        const bf16x8 wf0 = *(const bf16x8*)(w2t + (MT) * 1024);             \
        zA = MFMA(wf0, a10A, zA, 0, 0, 0);                                  \
        zB = MFMA(wf0, a10B, zB, 0, 0, 0);                                  \
        zC = MFMA(wf0, a10C, zC, 0, 0, 0);                                  \
        zD = MFMA(wf0, a10D, zD, 0, 0, 0);                                  \
        const bf16x8 wf1 = *(const bf16x8*)(w2t + (MT) * 1024 + 32);        \
        zA = MFMA(wf1, a11A, zA, 0, 0, 0);                                  \
        zB = MFMA(wf1, a11B, zB, 0, 0, 0);                                  \
        zC = MFMA(wf1, a11C, zC, 0, 0, 0);                                  \
        zD = MFMA(wf1, a11D, zD, 0, 0, 0);                                  \
        const float4 w3v = *(const float4*)(W3 + 16 * (MT) + 4 * hi);       \
        H2ONE(zA, vpA, g2A, MT);                                            \
        H2ONE(zB, vpB, g2B, MT);                                            \
        H2ONE(zC, vpC, g2C, MT);                                            \
        H2ONE(zD, vpD, g2D, MT);                                            \
    } while (0)

// backward one tile at m-tile MT: mask loaded from LDS (no tanh recompute)
#define DVONE(R, MK, MT, D1, D2)                                                              \
    do {                                                                                      \
        const bf16x4 mv = *(const bf16x4*)((MK) + rowbase + ((16 * (MT) + 4 * hi) ^ swz));    \
        float gi;                                                                             \
        gi = (float)mv[0] * R[0]; D1 = fmaf(w1av.x, gi, D1); D2 = fmaf(w1bv.x, gi, D2);       \
        gi = (float)mv[1] * R[1]; D1 = fmaf(w1av.y, gi, D1); D2 = fmaf(w1bv.y, gi, D2);       \
        gi = (float)mv[2] * R[2]; D1 = fmaf(w1av.z, gi, D1); D2 = fmaf(w1bv.z, gi, D2);       \
        gi = (float)mv[3] * R[3]; D1 = fmaf(w1av.w, gi, D1); D2 = fmaf(w1bv.w, gi, D2);       \
    } while (0)

// one backward m-tile: GEMM2 + mask/dV for all 4 tiles; accs die here
#define BWDMT(MT)                                                           \
    do {                                                                    \
        f32x4 rA = {0.f, 0.f, 0.f, 0.f};                                    \
        f32x4 rB = rA, rC = rA, rD = rA;                                    \
        const bf16x8 wf0 = *(const bf16x8*)(w2b + (MT) * 1024);             \
        rA = MFMA(wf0, a20A, rA, 0, 0, 0);                                  \
        rB = MFMA(wf0, a20B, rB, 0, 0, 0);                                  \
        rC = MFMA(wf0, a20C, rC, 0, 0, 0);                                  \
        rD = MFMA(wf0, a20D, rD, 0, 0, 0);                                  \
        const bf16x8 wf1 = *(const bf16x8*)(w2b + (MT) * 1024 + 32);        \
        rA = MFMA(wf1, a21A, rA, 0, 0, 0);                                  \
        rB = MFMA(wf1, a21B, rB, 0, 0, 0);                                  \
        rC = MFMA(wf1, a21C, rC, 0, 0, 0);                                  \
        rD = MFMA(wf1, a21D, rD, 0, 0, 0);                                  \
        const float4 w1av = *(const float4*)(W1 + 16 * (MT) + 4 * hi);      \
        const float4 w1bv = *(const float4*)(W1 + HID + 16 * (MT) + 4 * hi);\
        DVONE(rA, mkA, MT, d1A, d2A);                                       \
        DVONE(rB, mkB, MT, d1B, d2B);                                       \
        DVONE(rC, mkC, MT, d1C, d2C);                                       \
        DVONE(rD, mkD, MT, d1D, d2D);                                       \
    } while (0)

#define RED2(V) V += __shfl_xor(V, 16, 64); V += __shfl_xor(V, 32, 64);

#define SEL4(A, B, C, D) ((hi == 0) ? (A) : (hi == 1) ? (B) : (hi == 2) ? (C) : (D))

// ---- main: FOUR interleaved 16-row tiles per wave; bf16 masks in LDS ----
__global__ __launch_bounds__(256, 2) void pend_kernel(
    const float4* __restrict__ x,
    const float* __restrict__ W1, const float* __restrict__ b1,
    const __bf16* __restrict__ W2bf, const __bf16* __restrict__ W2Tbf,
    const float* __restrict__ b2,
    const float* __restrict__ W3, const float* __restrict__ b3,
    const float* __restrict__ Tp, const float* __restrict__ edes_p,
    float4* __restrict__ out, int n)
{
    __shared__ __align__(16) __bf16 lds[4 * 8192];  // per wave: g2 x4 (2KB) + mask x4 (2KB)
    const int tid = threadIdx.x;
    const int w = tid >> 6, l = tid & 63;
    const int lo = l & 15, hi = l >> 4;
    __bf16* g2A = lds + w * 8192;
    __bf16* g2B = g2A + 1024;
    __bf16* g2C = g2B + 1024;
    __bf16* g2D = g2C + 1024;
    __bf16* mkA = g2D + 1024;
    __bf16* mkB = mkA + 1024;
    __bf16* mkC = mkB + 1024;
    __bf16* mkD = mkC + 1024;

    const float E_des = edes_p[0];
    const float Tabs = fabsf(Tp[0]);
    const float b3c = b3[0];

    const int base = blockIdx.x * 256 + w * 64;   // 64 rows per wave
    int eA = base + lo;       if (eA >= n) eA = n - 1;
    int eB = base + 16 + lo;  if (eB >= n) eB = n - 1;
    int eC = base + 32 + lo;  if (eC >= n) eC = n - 1;
    int eD = base + 48 + lo;  if (eD >= n) eD = n - 1;
    const float4 xvA = x[eA];
    const float4 xvB = x[eB];
    const float4 xvC = x[eC];
    const float4 xvD = x[eD];
    const float q1A = xvA.x, q2A = xvA.y, p1A = xvA.z, p2A = xvA.w;
    const float q1B = xvB.x, q2B = xvB.y, p1B = xvB.z, p2B = xvB.w;
    const float q1C = xvC.x, q2C = xvC.y, p1C = xvC.z, p2C = xvC.w;
    const float q1D = xvD.x, q2D = xvD.y, p1D = xvD.z, p2D = xvD.w;

    const int swz = (lo & 7) << 3;          // XOR swizzle on j (bits 3..5)
    const int rowbase = lo * HID;

    // ---- layer-1 for 4 tiles (shared weight loads); masks stored to LDS ----
    bf16x8 a10A, a11A, a10B, a11B, a10C, a11C, a10D, a11D;
    L1HALF4(a10A, a10B, a10C, a10D, 8 * hi);
    L1HALF4(a11A, a11B, a11C, a11D, 32 + 8 * hi);

    const __bf16* w2t = W2Tbf + lo * HID + 8 * hi;   // + mt*1024 (+32 for kh=1)
    const __bf16* w2b = W2bf  + lo * HID + 8 * hi;

    // ---- forward: GEMM1 + h2/V/g2, one m-tile at a time (short acc lifetimes) ----
    float vpA = 0.0f, vpB = 0.0f, vpC = 0.0f, vpD = 0.0f;
    FWDMT(0);
    FWDMT(1);
    FWDMT(2);
    FWDMT(3);

    // ---- GEMM2 A-fragments from LDS (all g2 writes precede these reads, same wave) ----
    const bf16x8 a20A = *(const bf16x8*)(g2A + rowbase + ((8 * hi) ^ swz));
    const bf16x8 a21A = *(const bf16x8*)(g2A + rowbase + ((32 + 8 * hi) ^ swz));
    const bf16x8 a20B = *(const bf16x8*)(g2B + rowbase + ((8 * hi) ^ swz));
    const bf16x8 a21B = *(const bf16x8*)(g2B + rowbase + ((32 + 8 * hi) ^ swz));
    const bf16x8 a20C = *(const bf16x8*)(g2C + rowbase + ((8 * hi) ^ swz));
    const bf16x8 a21C = *(const bf16x8*)(g2C + rowbase + ((32 + 8 * hi) ^ swz));
    const bf16x8 a20D = *(const bf16x8*)(g2D + rowbase + ((8 * hi) ^ swz));
    const bf16x8 a21D = *(const bf16x8*)(g2D + rowbase + ((32 + 8 * hi) ^ swz));

    // ---- backward: GEMM2 + mask/dV, one m-tile at a time ----
    float d1A = 0.f, d2A = 0.f, d1B = 0.f, d2B = 0.f;
    float d1C = 0.f, d2C = 0.f, d1D = 0.f, d2D = 0.f;
    BWDMT(0);
    BWDMT(1);
    BWDMT(2);
    BWDMT(3);

    // ---- reduce over hi-groups; each lane then owns row base + l (tile = hi) ----
    RED2(vpA) RED2(vpB) RED2(vpC) RED2(vpD)
    RED2(d1A) RED2(d1B) RED2(d1C) RED2(d1D)
    RED2(d2A) RED2(d2B) RED2(d2C) RED2(d2D)

    const float V    = SEL4(vpA, vpB, vpC, vpD) + b3c;
    const float dVq1 = SEL4(d1A, d1B, d1C, d1D);
    const float dVq2 = SEL4(d2A, d2B, d2C, d2D);
    const float q1 = SEL4(q1A, q1B, q1C, q1D);
    const float q2 = SEL4(q2A, q2B, q2C, q2D);
    const float p1 = SEL4(p1A, p1B, p1C, p1D);
    const float p2 = SEL4(p2A, p2B, p2C, p2D);

    // ---- physics, once per lane (row = base + l) ----
    float s2q, c2q, s1q, c1q;
    __sincosf(q2, &s2q, &c2q);
    __sincosf(q1, &s1q, &c1q);
    const float s12 = s1q * c2q + c1q * s2q;
    const float c12 = c1q * c2q - s1q * s2q;

    const float cc = c2q, s = s2q;
    const float DEN = 2.0f - cc * cc;        // == 1 + s^2
    const float rDEN = __builtin_amdgcn_rcpf(DEN);
    const float cp1 = cc + 1.0f;

    const float quad = (p1 * p1 - 2.0f * cp1 * p1 * p2 + (2.0f * cc + 3.0f) * p2 * p2) * rDEN;
    const float kin = 0.5f * quad;
    const float dqa = 1.57079632679489662f - q2;
    const float pot = -9.81f * (c12 + 2.0f * c1q) + 0.5f * dqa * dqa;
    const float E = pot + kin + V;

    const float fac = (quad > 0.0f) ? __builtin_amdgcn_rsqf(quad) : 1.0f;
    const float coef = E_des - E;
    const float u1 = -dVq1 + coef * p1 * fac;
    const float u2 = -dVq2 + coef * p2 * fac;

    const float dq1dt = (p1 - cp1 * p2) * rDEN;
    const float dq2dt = ((2.0f * cc + 3.0f) * p2 - cp1 * p1) * rDEN;
    const float dp1dt = -9.81f * (s12 + 2.0f * s1q) + u1;

    const float inner = -p2 * p2 * s * cp1 * (cc + 2.0f)
                + p1 * p2 * s * (fmaf(cc, cc, fmaf(2.0f, cc, 2.0f)))
                - cc * p1 * p1 * s
                + DEN * DEN * (fmaf(9.81f, s12, -0.5f * (3.14159265358979324f - 2.0f * q2)));
    const float dp2dt = -(inner * rDEN * rDEN) + u2;

    const int row = base + l;
    if (row < n) {
        float4 o;
        o.x = Tabs * dq1dt;
        o.y = Tabs * dq2dt;
        o.z = Tabs * dp1dt;
        o.w = Tabs * dp2dt;
        out[row] = o;
    }
}

extern "C" void kernel_launch(void* const* d_in, const int* in_sizes, int n_in,
                              void* d_out, int out_size, void* d_ws, size_t ws_size,
                              hipStream_t stream) {
    const float* x  = (const float*)d_in[0];
    // d_in[1] = t (unused)
    const float* W1 = (const float*)d_in[2];
    const float* b1 = (const float*)d_in[3];
    const float* W2 = (const float*)d_in[4];
    const float* b2 = (const float*)d_in[5];
    const float* W3 = (const float*)d_in[6];
    const float* b3 = (const float*)d_in[7];
    const float* Tp = (const float*)d_in[8];
    const float* x0 = (const float*)d_in[9];

    float* ws = (float*)d_ws;
    float* edes = ws;                                   // 1 float (+ padding to 64B)
    __bf16* W2bf  = (__bf16*)(ws + 16);                 // 4096 bf16 = 8 KB
    __bf16* W2Tbf = W2bf + HID * HID;                   // 4096 bf16 = 8 KB

    prep_kernel<<<1, 256, 0, stream>>>(W1, b1, W2, b2, W3, b3, x0, edes, W2bf, W2Tbf);

    int n = in_sizes[0] / 4;  // 500000
    int blocks = (n + 255) / 256;  // 256 rows per block (4 waves x 4 tiles x 16) -> 1954
    pend_kernel<<<blocks, 256, 0, stream>>>((const float4*)x, W1, b1, W2bf, W2Tbf,
                                            b2, W3, b3, Tp, edes, (float4*)d_out, n);
}